// Round 2
// baseline (9886.276 us; speedup 1.0000x reference)
//
#include <hip/hip_runtime.h>
#include <stdint.h>

typedef unsigned short u16;
typedef __attribute__((ext_vector_type(8))) short short8;
typedef __attribute__((ext_vector_type(4))) float floatx4;

constexpr int BB = 128;     // batch
constexpr int TT = 64;      // time steps
constexpr int CC = 66;      // frame channels
constexpr int CPAD = 96;    // C padded to multiple of 32 (MFMA K-chunk)
constexpr int CPAD2 = 128;  // C padded for WsT epilogue GEMV
constexpr int SS = 512;     // hidden
constexpr int NGATE = 1536; // 3*S
constexpr int NBLK = 128;   // persistent-kernel blocks (<=256 CUs: co-resident)
constexpr int HS = BB * SS; // one hidden-state buffer, elements

__device__ __forceinline__ u16 f2bf(float f) {
    uint32_t u = __float_as_uint(f);
    uint32_t r = (u + 0x7fffu + ((u >> 16) & 1u)) >> 16;
    return (u16)r;
}
__device__ __forceinline__ float bf2f(u16 h) {
    return __uint_as_float(((uint32_t)h) << 16);
}
__device__ __forceinline__ float sigm(float x) { return 1.f / (1.f + __expf(-x)); }
__device__ __forceinline__ float tanh_f(float x) { return 1.f - 2.f / (1.f + __expf(2.f * x)); }

// ---------------------------------------------------------------------------
// One-time prep (parallel): fp32 -> bf16 conversion with zero padding, Ws
// transpose, decoder input init from x[:, T-1, :].  Identical to round 1.
// ---------------------------------------------------------------------------
__global__ void prep_kernel(const float* __restrict__ x,
                            const float* __restrict__ Wih0,
                            const float* __restrict__ Whh0,
                            const float* __restrict__ Wih1,
                            const float* __restrict__ Whh1,
                            const float* __restrict__ Ws,
                            u16* __restrict__ xbf, u16* __restrict__ wi0,
                            u16* __restrict__ wh0, u16* __restrict__ wi1,
                            u16* __restrict__ wh1, float* __restrict__ wst,
                            float* __restrict__ dinp_f, u16* __restrict__ dinp_bf)
{
    const int N_xbf = BB * TT * CPAD;
    const int N_wi0 = NGATE * CPAD;
    const int N_whh = NGATE * SS;
    const int N_wst = SS * CPAD2;
    const int N_dinp = BB * CPAD;
    const long total = (long)N_xbf + N_wi0 + 3L * N_whh + N_wst + N_dinp;
    for (long i = (long)blockIdx.x * blockDim.x + threadIdx.x; i < total;
         i += (long)gridDim.x * blockDim.x) {
        long idx = i;
        if (idx < N_xbf) {
            int c = idx % CPAD; int bt = idx / CPAD;
            float v = (c < CC) ? x[(long)bt * CC + c] : 0.f;
            xbf[idx] = f2bf(v); continue;
        }
        idx -= N_xbf;
        if (idx < N_wi0) {
            int c = idx % CPAD; int n = idx / CPAD;
            float v = (c < CC) ? Wih0[(long)n * CC + c] : 0.f;
            wi0[idx] = f2bf(v); continue;
        }
        idx -= N_wi0;
        if (idx < N_whh) { wh0[idx] = f2bf(Whh0[idx]); continue; }
        idx -= N_whh;
        if (idx < N_whh) { wi1[idx] = f2bf(Wih1[idx]); continue; }
        idx -= N_whh;
        if (idx < N_whh) { wh1[idx] = f2bf(Whh1[idx]); continue; }
        idx -= N_whh;
        if (idx < N_wst) {
            int c = idx % CPAD2; int s = idx / CPAD2;
            wst[idx] = (c < CC) ? Ws[(long)c * SS + s] : 0.f;
            continue;
        }
        idx -= N_wst;
        {
            int c = idx % CPAD; int b = idx / CPAD;
            float v = (c < CC) ? x[((long)b * TT + (TT - 1)) * CC + c] : 0.f;
            dinp_bf[idx] = f2bf(v);
            if (c < CC) dinp_f[(long)b * CC + c] = v;
        }
    }
}

// ---------------------------------------------------------------------------
// Device-scope epoch barrier.  All NBLK blocks co-resident (128 <= 256 CUs).
// Release: per-thread __threadfence() drains each wave's stores to device
// scope before arrival.  Acquire: epoch load + per-thread fence invalidates
// L1 so post-barrier loads are fresh (G16).
// ---------------------------------------------------------------------------
__device__ __forceinline__ void grid_barrier(int* cnt, int* ep, int target) {
    __threadfence();
    __syncthreads();
    if (threadIdx.x == 0) {
        int old = __hip_atomic_fetch_add(cnt, 1, __ATOMIC_ACQ_REL,
                                         __HIP_MEMORY_SCOPE_AGENT);
        if (old == NBLK - 1) {
            __hip_atomic_store(cnt, 0, __ATOMIC_RELAXED, __HIP_MEMORY_SCOPE_AGENT);
            __hip_atomic_fetch_add(ep, 1, __ATOMIC_RELEASE,
                                   __HIP_MEMORY_SCOPE_AGENT);
        } else {
            while (__hip_atomic_load(ep, __ATOMIC_ACQUIRE,
                                     __HIP_MEMORY_SCOPE_AGENT) < target) {
                __builtin_amdgcn_s_sleep(1);
            }
        }
    }
    __syncthreads();
    __threadfence();
}

// ---------------------------------------------------------------------------
// Fused GRU cell phase (device fn).  blk in [0,64): bg = blk&3 (b-group of
// 32), sg = blk>>2 (s-tile of 32).  4 waves = 4 (16b x 16s) quadrants.
// Math identical to round 1's gru_cell_kernel.
// ---------------------------------------------------------------------------
template <int KIN>
__device__ void gru_phase(int blk,
    const u16* __restrict__ Abf, int ldA,
    const u16* __restrict__ Wibf,
    const u16* __restrict__ Hbf,
    const u16* __restrict__ Whbf,
    const float* __restrict__ bih, const float* __restrict__ bhh,
    const float* __restrict__ hold_f,
    float* __restrict__ hnew_f, u16* __restrict__ hnew_bf,
    u16* __restrict__ win_slot)
{
    const int tid = threadIdx.x;
    const int wave = tid >> 6, lane = tid & 63;
    const int msub = wave & 1, ssub = wave >> 1;
    const int b0 = (blk & 3) * 32 + msub * 16;
    const int s0 = (blk >> 2) * 32 + ssub * 16;
    const int l15 = lane & 15, quad = lane >> 4;

    floatx4 accR = {0.f, 0.f, 0.f, 0.f};
    floatx4 accZ = accR, accNI = accR, accNH = accR;

    {   // x-phase
        const u16* aP  = Abf + (long)(b0 + l15) * ldA + quad * 8;
        const u16* wrP = Wibf + (long)(s0 + l15) * KIN + quad * 8;
        const u16* wzP = Wibf + (long)(512 + s0 + l15) * KIN + quad * 8;
        const u16* wnP = Wibf + (long)(1024 + s0 + l15) * KIN + quad * 8;
#pragma unroll
        for (int k = 0; k < KIN; k += 32) {
            short8 a  = *(const short8*)(aP + k);
            short8 br = *(const short8*)(wrP + k);
            short8 bz = *(const short8*)(wzP + k);
            short8 bn = *(const short8*)(wnP + k);
            accR  = __builtin_amdgcn_mfma_f32_16x16x32_bf16(a, br, accR, 0, 0, 0);
            accZ  = __builtin_amdgcn_mfma_f32_16x16x32_bf16(a, bz, accZ, 0, 0, 0);
            accNI = __builtin_amdgcn_mfma_f32_16x16x32_bf16(a, bn, accNI, 0, 0, 0);
        }
    }
    {   // h-phase
        const u16* hP  = Hbf + (long)(b0 + l15) * SS + quad * 8;
        const u16* wrP = Whbf + (long)(s0 + l15) * SS + quad * 8;
        const u16* wzP = Whbf + (long)(512 + s0 + l15) * SS + quad * 8;
        const u16* wnP = Whbf + (long)(1024 + s0 + l15) * SS + quad * 8;
#pragma unroll
        for (int k = 0; k < SS; k += 32) {
            short8 a  = *(const short8*)(hP + k);
            short8 br = *(const short8*)(wrP + k);
            short8 bz = *(const short8*)(wzP + k);
            short8 bn = *(const short8*)(wnP + k);
            accR  = __builtin_amdgcn_mfma_f32_16x16x32_bf16(a, br, accR, 0, 0, 0);
            accZ  = __builtin_amdgcn_mfma_f32_16x16x32_bf16(a, bz, accZ, 0, 0, 0);
            accNH = __builtin_amdgcn_mfma_f32_16x16x32_bf16(a, bn, accNH, 0, 0, 0);
        }
    }
    const int s = s0 + l15;
    const float bir = bih[s] + bhh[s];
    const float biz = bih[512 + s] + bhh[512 + s];
    const float bin = bih[1024 + s];
    const float bhn = bhh[1024 + s];
#pragma unroll
    for (int r = 0; r < 4; ++r) {
        const int b = b0 + quad * 4 + r;
        float rr = sigm(accR[r] + bir);
        float zz = sigm(accZ[r] + biz);
        float nn = tanh_f(accNI[r] + bin + rr * (accNH[r] + bhn));
        float ho = hold_f[(long)b * SS + s];
        float hv = (1.f - zz) * nn + zz * ho;
        hnew_f[(long)b * SS + s] = hv;
        u16 hb = f2bf(hv);
        hnew_bf[(long)b * SS + s] = hb;
        if (win_slot) win_slot[(long)b * SS + s] = hb;
    }
}

// ---------------------------------------------------------------------------
// Decoder output phase (device fn): one block per batch element b = blk.
// Identical math to round 1's out_step_kernel.
// ---------------------------------------------------------------------------
__device__ void out_phase(int b, int d,
    const u16* __restrict__ winb,
    const float* __restrict__ Wt, const float* __restrict__ bt,
    const float* __restrict__ wst, const float* __restrict__ bs,
    float* __restrict__ dinp_f, u16* __restrict__ dinp_bf,
    float* __restrict__ outp)
{
    __shared__ float ts[SS];
    __shared__ float red[4][CPAD2];
    __shared__ float wts[32];
    const int tid = threadIdx.x;
    if (tid < 32) wts[tid] = Wt[tid];
    __syncthreads();
    const float btv = bt[0];
    for (int s = tid; s < SS; s += 256) {
        float acc = btv;
#pragma unroll
        for (int j = 0; j < 32; ++j) {
            int slot = (1 + d + j) & 31;
            acc += bf2f(winb[(long)slot * HS + (long)b * SS + s]) * wts[j];
        }
        ts[s] = acc;
    }
    __syncthreads();
    const int w = tid >> 6, lane = tid & 63;
    float a0 = 0.f, a1 = 0.f;
    for (int s = w * 128; s < w * 128 + 128; ++s) {
        float tv = ts[s];
        a0 += tv * wst[(long)s * CPAD2 + lane];
        a1 += tv * wst[(long)s * CPAD2 + 64 + lane];
    }
    red[w][lane] = a0;
    red[w][64 + lane] = a1;
    __syncthreads();
    if (tid < CC) {
        const int c = tid;
        float v = bs[c] + red[0][c] + red[1][c] + red[2][c] + red[3][c];
        float fr = v + dinp_f[(long)b * CC + c];
        outp[(long)b * (TT * CC) + (long)d * CC + c] = fr;
        dinp_f[(long)b * CC + c] = fr;
        dinp_bf[(long)b * CPAD + c] = f2bf(fr);
    }
    __syncthreads();
}

// ---------------------------------------------------------------------------
// Persistent kernel: all 127 steps, device-scope barriers between phases.
// Encoder 2-deep pipeline: phase p = { L0(p) on blocks 0..63 || L1(p-1) on
// blocks 64..127 }  ->  64 barriers.  Decoder: L0, L1, out  ->  192 barriers.
// ---------------------------------------------------------------------------
__global__ __launch_bounds__(256) void persist_kernel(
    const u16* __restrict__ xbf,
    const u16* __restrict__ wi0, const u16* __restrict__ wh0,
    const u16* __restrict__ wi1, const u16* __restrict__ wh1,
    const float* __restrict__ bih0, const float* __restrict__ bhh0,
    const float* __restrict__ bih1, const float* __restrict__ bhh1,
    const float* __restrict__ Wt, const float* __restrict__ bt,
    const float* __restrict__ wst, const float* __restrict__ bs,
    float* __restrict__ h0f, u16* __restrict__ h0b,   // each: 2 buffers of HS
    float* __restrict__ h1f, u16* __restrict__ h1b,
    u16* __restrict__ winb,
    float* __restrict__ dinp_f, u16* __restrict__ dinp_bf,
    float* __restrict__ outp,
    int* __restrict__ bar_cnt, int* __restrict__ bar_ep)
{
    const int blk = blockIdx.x;
    int bar = 0;
    int c0 = 0, c1 = 0;   // index of newest h0 / h1 buffer

    // ---- encoder: phases p = 0..63 ----
    for (int p = 0; p < 64; ++p) {
        if (blk < 64) {
            if (p < 63)
                gru_phase<CPAD>(blk, xbf + (long)p * CPAD, TT * CPAD, wi0,
                                h0b + (long)c0 * HS, wh0, bih0, bhh0,
                                h0f + (long)c0 * HS,
                                h0f + (long)(1 - c0) * HS,
                                h0b + (long)(1 - c0) * HS, nullptr);
        } else {
            if (p >= 1) {
                const int t = p - 1;
                u16* wslot = (t >= 31) ? (winb + (size_t)(t - 31) * HS) : nullptr;
                gru_phase<SS>(blk - 64, h0b + (long)c0 * HS, SS, wi1,
                              h1b + (long)c1 * HS, wh1, bih1, bhh1,
                              h1f + (long)c1 * HS,
                              h1f + (long)(1 - c1) * HS,
                              h1b + (long)(1 - c1) * HS, wslot);
            }
        }
        grid_barrier(bar_cnt, bar_ep, ++bar);
        if (p < 63) c0 ^= 1;
        if (p >= 1) c1 ^= 1;
    }

    // ---- decoder: d = 0..63, 3 phases each ----
    for (int d = 0; d < 64; ++d) {
        if (blk < 64)
            gru_phase<CPAD>(blk, dinp_bf, CPAD, wi0,
                            h0b + (long)c0 * HS, wh0, bih0, bhh0,
                            h0f + (long)c0 * HS,
                            h0f + (long)(1 - c0) * HS,
                            h0b + (long)(1 - c0) * HS, nullptr);
        grid_barrier(bar_cnt, bar_ep, ++bar);
        c0 ^= 1;

        if (blk < 64)
            gru_phase<SS>(blk, h0b + (long)c0 * HS, SS, wi1,
                          h1b + (long)c1 * HS, wh1, bih1, bhh1,
                          h1f + (long)c1 * HS,
                          h1f + (long)(1 - c1) * HS,
                          h1b + (long)(1 - c1) * HS,
                          winb + (size_t)(d & 31) * HS);
        grid_barrier(bar_cnt, bar_ep, ++bar);
        c1 ^= 1;

        out_phase(blk, d, winb, Wt, bt, wst, bs, dinp_f, dinp_bf, outp);
        grid_barrier(bar_cnt, bar_ep, ++bar);
    }
}

// ---------------------------------------------------------------------------
extern "C" void kernel_launch(void* const* d_in, const int* in_sizes, int n_in,
                              void* d_out, int out_size, void* d_ws, size_t ws_size,
                              hipStream_t stream)
{
    const float* x    = (const float*)d_in[0];
    const float* Wih0 = (const float*)d_in[1];
    const float* Whh0 = (const float*)d_in[2];
    const float* bih0 = (const float*)d_in[3];
    const float* bhh0 = (const float*)d_in[4];
    const float* Wih1 = (const float*)d_in[5];
    const float* Whh1 = (const float*)d_in[6];
    const float* bih1 = (const float*)d_in[7];
    const float* bhh1 = (const float*)d_in[8];
    const float* Wt   = (const float*)d_in[9];
    const float* bt   = (const float*)d_in[10];
    const float* Ws   = (const float*)d_in[11];
    const float* bs   = (const float*)d_in[12];
    float* outp = (float*)d_out;

    char* p = (char*)d_ws;
    auto alloc = [&](size_t bytes) -> char* {
        char* r = p; p += (bytes + 255) & ~(size_t)255; return r;
    };
    float* h0f = (float*)alloc(2L * HS * 4);
    float* h1f = (float*)alloc(2L * HS * 4);
    u16* h0b = (u16*)alloc(2L * HS * 2);
    u16* h1b = (u16*)alloc(2L * HS * 2);
    u16* xbf = (u16*)alloc((size_t)BB * TT * CPAD * 2);
    u16* wi0 = (u16*)alloc((size_t)NGATE * CPAD * 2);
    u16* wh0 = (u16*)alloc((size_t)NGATE * SS * 2);
    u16* wi1 = (u16*)alloc((size_t)NGATE * SS * 2);
    u16* wh1 = (u16*)alloc((size_t)NGATE * SS * 2);
    float* wst = (float*)alloc((size_t)SS * CPAD2 * 4);
    u16* winb = (u16*)alloc((size_t)32 * HS * 2);
    float* dinp_f = (float*)alloc(BB * CC * 4);
    u16* dinp_bf = (u16*)alloc(BB * CPAD * 2);
    int* bar = (int*)alloc(256);   // [0]=cnt, [1]=epoch

    // zero initial hidden state + barrier state (ws poisoned each call)
    hipMemsetAsync(h0f, 0, 2L * HS * 4, stream);
    hipMemsetAsync(h1f, 0, 2L * HS * 4, stream);
    hipMemsetAsync(h0b, 0, 2L * HS * 2, stream);
    hipMemsetAsync(h1b, 0, 2L * HS * 2, stream);
    hipMemsetAsync(bar, 0, 256, stream);

    prep_kernel<<<1024, 256, 0, stream>>>(x, Wih0, Whh0, Wih1, Whh1, Ws,
                                          xbf, wi0, wh0, wi1, wh1, wst,
                                          dinp_f, dinp_bf);

    persist_kernel<<<NBLK, 256, 0, stream>>>(
        xbf, wi0, wh0, wi1, wh1, bih0, bhh0, bih1, bhh1,
        Wt, bt, wst, bs, h0f, h0b, h1f, h1b, winb,
        dinp_f, dinp_bf, outp, bar, bar + 1);
}

// Round 3
// 7716.210 us; speedup vs baseline: 1.2812x; 1.2812x over previous
//
#include <hip/hip_runtime.h>
#include <stdint.h>

typedef unsigned short u16;
typedef __attribute__((ext_vector_type(8))) short short8;
typedef __attribute__((ext_vector_type(4))) float floatx4;

constexpr int BB = 128;     // batch
constexpr int TT = 64;      // time steps
constexpr int CC = 66;      // frame channels
constexpr int CPAD = 96;    // C padded to multiple of 32 (MFMA K-chunk)
constexpr int SS = 512;     // hidden
constexpr int NGATE = 1536; // 3*S
constexpr int NBLK = 128;   // persistent blocks (<=256 CUs -> co-resident)
constexpr int HS = BB * SS;

__device__ __forceinline__ u16 f2bf(float f) {
    uint32_t u = __float_as_uint(f);
    uint32_t r = (u + 0x7fffu + ((u >> 16) & 1u)) >> 16;
    return (u16)r;
}
__device__ __forceinline__ float bf2f(u16 h) {
    return __uint_as_float(((uint32_t)h) << 16);
}
__device__ __forceinline__ float sigm(float x) { return 1.f / (1.f + __expf(-x)); }
__device__ __forceinline__ float tanh_f(float x) { return 1.f - 2.f / (1.f + __expf(2.f * x)); }

// ---------------------------------------------------------------------------
// prep1: bf16 conversion of x (padded to 96) and the 4 GRU weight matrices.
// ---------------------------------------------------------------------------
__global__ void prep1_kernel(const float* __restrict__ x,
                             const float* __restrict__ Wih0,
                             const float* __restrict__ Whh0,
                             const float* __restrict__ Wih1,
                             const float* __restrict__ Whh1,
                             u16* __restrict__ xbf, u16* __restrict__ wi0,
                             u16* __restrict__ wh0, u16* __restrict__ wi1,
                             u16* __restrict__ wh1)
{
    const int N_xbf = BB * TT * CPAD;
    const int N_wi0 = NGATE * CPAD;
    const int N_whh = NGATE * SS;
    const long total = (long)N_xbf + N_wi0 + 3L * N_whh;
    for (long i = (long)blockIdx.x * blockDim.x + threadIdx.x; i < total;
         i += (long)gridDim.x * blockDim.x) {
        long idx = i;
        if (idx < N_xbf) {
            int c = idx % CPAD; int bt = idx / CPAD;
            float v = (c < CC) ? x[(long)bt * CC + c] : 0.f;
            xbf[idx] = f2bf(v); continue;
        }
        idx -= N_xbf;
        if (idx < N_wi0) {
            int c = idx % CPAD; int n = idx / CPAD;
            float v = (c < CC) ? Wih0[(long)n * CC + c] : 0.f;
            wi0[idx] = f2bf(v); continue;
        }
        idx -= N_wi0;
        if (idx < N_whh) { wh0[idx] = f2bf(Whh0[idx]); continue; }
        idx -= N_whh;
        if (idx < N_whh) { wi1[idx] = f2bf(Wih1[idx]); continue; }
        idx -= N_whh;
        wh1[idx] = f2bf(Whh1[idx]);
    }
}

// ---------------------------------------------------------------------------
// prep2: M = Wih0[:, :66] @ Ws  (bf16, [1536][512]);  c0vec = Wih0 @ bs;
//        gi0i[b][g] = sum_c x[b, T-1, c] * Wih0[g][c]  (fp32, [128][1536]).
// ---------------------------------------------------------------------------
__global__ void prep2_kernel(const float* __restrict__ x,
                             const float* __restrict__ Wih0,
                             const float* __restrict__ Ws,
                             const float* __restrict__ bs,
                             u16* __restrict__ Mbf, float* __restrict__ c0vec,
                             float* __restrict__ gi0i)
{
    const long NM = (long)NGATE * SS;        // 786432
    const long NC = NGATE;                   // 1536
    const long NG = (long)BB * NGATE;        // 196608
    const long total = NM + NC + NG;
    for (long i = (long)blockIdx.x * blockDim.x + threadIdx.x; i < total;
         i += (long)gridDim.x * blockDim.x) {
        long idx = i;
        if (idx < NM) {
            int s = idx % SS; int g = idx / SS;
            float acc = 0.f;
            for (int c = 0; c < CC; ++c)
                acc += Wih0[(long)g * CC + c] * Ws[(long)c * SS + s];
            Mbf[idx] = f2bf(acc); continue;
        }
        idx -= NM;
        if (idx < NC) {
            int g = idx;
            float acc = 0.f;
            for (int c = 0; c < CC; ++c) acc += Wih0[(long)g * CC + c] * bs[c];
            c0vec[g] = acc; continue;
        }
        idx -= NC;
        {
            int g = idx % NGATE; int b = idx / NGATE;
            float acc = 0.f;
            const float* xl = x + ((long)b * TT + (TT - 1)) * CC;
            for (int c = 0; c < CC; ++c) acc += xl[c] * Wih0[(long)g * CC + c];
            gi0i[idx] = acc;
        }
    }
}

// ---------------------------------------------------------------------------
// Fast grid barrier: per-block arrival slots (distinct cachelines, relaxed
// stores, NO RMW), block-0 wave-0 polls all slots relaxed, monotone epoch
// release, spinners poll relaxed + single acquire fence on exit.
// ---------------------------------------------------------------------------
__device__ __forceinline__ void gbar(int* __restrict__ arrive,
                                     int* __restrict__ ep, int target) {
    __threadfence();   // release: drain + writeback dirty L2 (cross-XCD vis)
    __syncthreads();
    if (blockIdx.x == 0) {
        if (threadIdx.x < 64) {
            const int lane = threadIdx.x;
            if (lane == 0)
                __hip_atomic_store(&arrive[0], target, __ATOMIC_RELAXED,
                                   __HIP_MEMORY_SCOPE_AGENT);
            for (;;) {
                int v0 = __hip_atomic_load(&arrive[lane * 16], __ATOMIC_RELAXED,
                                           __HIP_MEMORY_SCOPE_AGENT);
                int v1 = __hip_atomic_load(&arrive[(lane + 64) * 16],
                                           __ATOMIC_RELAXED,
                                           __HIP_MEMORY_SCOPE_AGENT);
                if (__all(v0 >= target && v1 >= target)) break;
                __builtin_amdgcn_s_sleep(1);
            }
            if (lane == 0)
                __hip_atomic_store(ep, target, __ATOMIC_RELAXED,
                                   __HIP_MEMORY_SCOPE_AGENT);
        }
        __syncthreads();
    } else {
        if (threadIdx.x == 0) {
            __hip_atomic_store(&arrive[blockIdx.x * 16], target,
                               __ATOMIC_RELAXED, __HIP_MEMORY_SCOPE_AGENT);
            while (__hip_atomic_load(ep, __ATOMIC_RELAXED,
                                     __HIP_MEMORY_SCOPE_AGENT) < target)
                __builtin_amdgcn_s_sleep(1);
        }
        __syncthreads();
    }
    __builtin_amdgcn_fence(__ATOMIC_ACQUIRE, "agent");  // invalidate caches
}

// ---------------------------------------------------------------------------
// Triple-gate MFMA accumulate over K (A row-major ld, W rows K-contiguous).
// ---------------------------------------------------------------------------
template <int K>
__device__ __forceinline__ void mm3(const u16* __restrict__ aP,
                                    const u16* __restrict__ w0,
                                    const u16* __restrict__ w1,
                                    const u16* __restrict__ w2,
                                    floatx4& A0, floatx4& A1, floatx4& A2) {
#pragma unroll
    for (int k = 0; k < K; k += 32) {
        short8 a = *(const short8*)(aP + k);
        A0 = __builtin_amdgcn_mfma_f32_16x16x32_bf16(a, *(const short8*)(w0 + k), A0, 0, 0, 0);
        A1 = __builtin_amdgcn_mfma_f32_16x16x32_bf16(a, *(const short8*)(w1 + k), A1, 0, 0, 0);
        A2 = __builtin_amdgcn_mfma_f32_16x16x32_bf16(a, *(const short8*)(w2 + k), A2, 0, 0, 0);
    }
}

// ---------------------------------------------------------------------------
// Persistent kernel.  Blocks 0..63 = layer-0 tiles, 64..127 = layer-1 tiles.
// Stable (block,thread) -> (b,s) ownership keeps fp32 h and gi0 in REGISTERS.
// Encoder: 64 phases (L0 || L1 pipelined 2-deep).  Decoder: 2 phases/step.
// L1 blocks hold the 32-slot sliding window in LDS and emit temp(d) bf16.
// ---------------------------------------------------------------------------
__global__ __launch_bounds__(256) void persist_kernel(
    const u16* __restrict__ xbf,
    const u16* __restrict__ wi0, const u16* __restrict__ wh0,
    const u16* __restrict__ wi1, const u16* __restrict__ wh1,
    const u16* __restrict__ Mbf,
    const float* __restrict__ bih0, const float* __restrict__ bhh0,
    const float* __restrict__ bih1, const float* __restrict__ bhh1,
    const float* __restrict__ c0vec, const float* __restrict__ gi0i,
    const float* __restrict__ Wt, const float* __restrict__ bt,
    u16* __restrict__ h0b, u16* __restrict__ h1b,      // 2 buffers each
    u16* __restrict__ temps,                           // [64][128][512] bf16
    int* __restrict__ arrive, int* __restrict__ ep)
{
    __shared__ u16 win[32 * 32 * 32];   // [b_local][s_local][slot], 64 KB

    const int tid = threadIdx.x;
    const int wave = tid >> 6, lane = tid & 63;
    const int msub = wave & 1, ssub = wave >> 1;
    const int l15 = lane & 15, quad = lane >> 4;
    const bool isL0 = blockIdx.x < 64;
    const int blk2 = isL0 ? blockIdx.x : blockIdx.x - 64;
    const int b0 = (blk2 & 3) * 32 + msub * 16;
    const int s0 = (blk2 >> 2) * 32 + ssub * 16;
    const int s = s0 + l15;

    // ---- per-thread constants & register state ----
    float bir, biz, bin, bhn;        // biases for this block's layer
    float c0r = 0.f, c0z = 0.f, c0n = 0.f;
    float hf[4] = {0.f, 0.f, 0.f, 0.f};   // fp32 hidden state (register)
    float gi[12];                          // L0: running Wih0@frame (no bias)
    float wt[32]; float btv = 0.f;         // L1: temporal weights

    if (isL0) {
        bir = bih0[s] + bhh0[s];
        biz = bih0[512 + s] + bhh0[512 + s];
        bin = bih0[1024 + s];
        bhn = bhh0[1024 + s];
        c0r = c0vec[s]; c0z = c0vec[512 + s]; c0n = c0vec[1024 + s];
#pragma unroll
        for (int g = 0; g < 3; ++g)
#pragma unroll
            for (int r = 0; r < 4; ++r)
                gi[g * 4 + r] = gi0i[(long)(b0 + quad * 4 + r) * NGATE + g * 512 + s];
    } else {
        bir = bih1[s] + bhh1[s];
        biz = bih1[512 + s] + bhh1[512 + s];
        bin = bih1[1024 + s];
        bhn = bhh1[1024 + s];
#pragma unroll
        for (int j = 0; j < 32; ++j) wt[j] = Wt[j];
        btv = bt[0];
    }

    // weight row pointers (K-contiguous rows, fragment layout verified)
    const u16 *wiR, *wiZ, *wiN, *whR, *whZ, *whN, *mR, *mZ, *mN;
    if (isL0) {
        wiR = wi0 + (long)s * CPAD + quad * 8;
        wiZ = wi0 + (long)(512 + s) * CPAD + quad * 8;
        wiN = wi0 + (long)(1024 + s) * CPAD + quad * 8;
        whR = wh0 + (long)s * SS + quad * 8;
        whZ = wh0 + (long)(512 + s) * SS + quad * 8;
        whN = wh0 + (long)(1024 + s) * SS + quad * 8;
        mR = Mbf + (long)s * SS + quad * 8;
        mZ = Mbf + (long)(512 + s) * SS + quad * 8;
        mN = Mbf + (long)(1024 + s) * SS + quad * 8;
    } else {
        wiR = wi1 + (long)s * SS + quad * 8;
        wiZ = wi1 + (long)(512 + s) * SS + quad * 8;
        wiN = wi1 + (long)(1024 + s) * SS + quad * 8;
        whR = wh1 + (long)s * SS + quad * 8;
        whZ = wh1 + (long)(512 + s) * SS + quad * 8;
        whN = wh1 + (long)(1024 + s) * SS + quad * 8;
        mR = mZ = mN = nullptr;
    }

    int c0p = 0, c1p = 0, bar = 0;

    // ================= encoder: phases p = 0..63 =================
    for (int p = 0; p < 64; ++p) {
        if (isL0) {
            if (p < 63) {
                floatx4 aR = {0,0,0,0}, aZ = aR, aNI = aR, aNH = aR;
                const u16* aP = xbf + ((long)(b0 + l15) * TT + p) * CPAD + quad * 8;
                mm3<CPAD>(aP, wiR, wiZ, wiN, aR, aZ, aNI);
                const u16* hP = h0b + (long)c0p * HS + (long)(b0 + l15) * SS + quad * 8;
                mm3<SS>(hP, whR, whZ, whN, aR, aZ, aNH);
                u16* hN = h0b + (long)(1 - c0p) * HS;
#pragma unroll
                for (int r = 0; r < 4; ++r) {
                    float rr = sigm(aR[r] + bir);
                    float zz = sigm(aZ[r] + biz);
                    float nn = tanh_f(aNI[r] + bin + rr * (aNH[r] + bhn));
                    float hv = (1.f - zz) * nn + zz * hf[r];
                    hf[r] = hv;
                    hN[(long)(b0 + quad * 4 + r) * SS + s] = f2bf(hv);
                }
            }
        } else {
            if (p >= 1) {
                const int t = p - 1;
                floatx4 aR = {0,0,0,0}, aZ = aR, aNI = aR, aNH = aR;
                const u16* aP = h0b + (long)c0p * HS + (long)(b0 + l15) * SS + quad * 8;
                mm3<SS>(aP, wiR, wiZ, wiN, aR, aZ, aNI);
                const u16* hP = h1b + (long)c1p * HS + (long)(b0 + l15) * SS + quad * 8;
                mm3<SS>(hP, whR, whZ, whN, aR, aZ, aNH);
                u16* hN = h1b + (long)(1 - c1p) * HS;
                const int wslot = t - 31;
#pragma unroll
                for (int r = 0; r < 4; ++r) {
                    float rr = sigm(aR[r] + bir);
                    float zz = sigm(aZ[r] + biz);
                    float nn = tanh_f(aNI[r] + bin + rr * (aNH[r] + bhn));
                    float hv = (1.f - zz) * nn + zz * hf[r];
                    hf[r] = hv;
                    u16 hb = f2bf(hv);
                    hN[(long)(b0 + quad * 4 + r) * SS + s] = hb;
                    if (wslot >= 0) {
                        const int bl = msub * 16 + quad * 4 + r;
                        const int sl = ssub * 16 + l15;
                        win[(bl * 32 + sl) * 32 + wslot] = hb;
                    }
                }
            }
        }
        gbar(arrive, ep, ++bar);
        if (p < 63) c0p ^= 1;
        if (p >= 1) c1p ^= 1;
    }

    // ================= decoder: d = 0..63, 2 phases each =================
    for (int d = 0; d < 64; ++d) {
        // ---- phase A: layer 0 on blocks 0..63 ----
        if (isL0) {
            if (d > 0) {   // gi(d) = gi(d-1) + M @ temp(d-1) + c0
                floatx4 tR = {0,0,0,0}, tZ = tR, tN = tR;
                const u16* aP = temps + (long)(d - 1) * HS + (long)(b0 + l15) * SS + quad * 8;
                mm3<SS>(aP, mR, mZ, mN, tR, tZ, tN);
#pragma unroll
                for (int r = 0; r < 4; ++r) {
                    gi[r] += tR[r] + c0r;
                    gi[4 + r] += tZ[r] + c0z;
                    gi[8 + r] += tN[r] + c0n;
                }
            }
            floatx4 hR = {0,0,0,0}, hZ = hR, hN4 = hR;
            const u16* hP = h0b + (long)c0p * HS + (long)(b0 + l15) * SS + quad * 8;
            mm3<SS>(hP, whR, whZ, whN, hR, hZ, hN4);
            u16* hN = h0b + (long)(1 - c0p) * HS;
#pragma unroll
            for (int r = 0; r < 4; ++r) {
                float rr = sigm(gi[r] + hR[r] + bir);
                float zz = sigm(gi[4 + r] + hZ[r] + biz);
                float nn = tanh_f(gi[8 + r] + bin + rr * (hN4[r] + bhn));
                float hv = (1.f - zz) * nn + zz * hf[r];
                hf[r] = hv;
                hN[(long)(b0 + quad * 4 + r) * SS + s] = f2bf(hv);
            }
        }
        gbar(arrive, ep, ++bar);
        c0p ^= 1;

        // ---- phase B: layer 1 + window/temp on blocks 64..127 ----
        if (!isL0) {
            floatx4 aR = {0,0,0,0}, aZ = aR, aNI = aR, aNH = aR;
            const u16* aP = h0b + (long)c0p * HS + (long)(b0 + l15) * SS + quad * 8;
            mm3<SS>(aP, wiR, wiZ, wiN, aR, aZ, aNI);
            const u16* hP = h1b + (long)c1p * HS + (long)(b0 + l15) * SS + quad * 8;
            mm3<SS>(hP, whR, whZ, whN, aR, aZ, aNH);
            u16* hN = h1b + (long)(1 - c1p) * HS;
            u16* tOut = temps + (long)d * HS;
            const int slot_new = d & 31;
#pragma unroll
            for (int r = 0; r < 4; ++r) {
                float rr = sigm(aR[r] + bir);
                float zz = sigm(aZ[r] + biz);
                float nn = tanh_f(aNI[r] + bin + rr * (aNH[r] + bhn));
                float hv = (1.f - zz) * nn + zz * hf[r];
                hf[r] = hv;
                u16 hb = f2bf(hv);
                const int b = b0 + quad * 4 + r;
                hN[(long)b * SS + s] = hb;
                const int bl = msub * 16 + quad * 4 + r;
                const int sl = ssub * 16 + l15;
                const int cell = (bl * 32 + sl) * 32;
                win[cell + slot_new] = hb;
                float tacc = btv;
#pragma unroll
                for (int j = 0; j < 32; ++j)
                    tacc += bf2f(win[cell + ((1 + d + j) & 31)]) * wt[j];
                tOut[(long)b * SS + s] = f2bf(tacc);
            }
        }
        gbar(arrive, ep, ++bar);
        c1p ^= 1;
    }
}

// ---------------------------------------------------------------------------
// frames epilogue (parallel): frames[b][e][c] = x_last[b][c]
//      + sum_{e'<=e} ( sum_s temp(e')[b][s]*Ws[c][s] + bs[c] )
// One block per b; threads = (s-chunk 0..3) x (c-slot 0..63).
// ---------------------------------------------------------------------------
__global__ __launch_bounds__(256) void frames_kernel(
    const u16* __restrict__ temps, const float* __restrict__ x,
    const float* __restrict__ Ws, const float* __restrict__ bs,
    float* __restrict__ outp)
{
    const int b = blockIdx.x, tid = threadIdx.x;
    const int sc = tid >> 6, cs = tid & 63;
    __shared__ float part[4][128];
    float cum0 = x[((long)b * TT + (TT - 1)) * CC + cs];
    float cum1 = (cs < CC - 64) ? x[((long)b * TT + (TT - 1)) * CC + 64 + cs] : 0.f;
    const float bs0 = bs[cs];
    const float bs1 = (cs < CC - 64) ? bs[64 + cs] : 0.f;
    for (int e = 0; e < TT; ++e) {
        const u16* tr = temps + (long)e * HS + (long)b * SS + sc * 128;
        float p0 = 0.f, p1 = 0.f;
        for (int i = 0; i < 128; ++i) {
            float tv = bf2f(tr[i]);
            p0 += tv * Ws[(long)cs * SS + sc * 128 + i];
            if (cs < CC - 64) p1 += tv * Ws[(long)(64 + cs) * SS + sc * 128 + i];
        }
        part[sc][cs] = p0;
        part[sc][64 + cs] = p1;
        __syncthreads();
        if (sc == 0) {
            cum0 += part[0][cs] + part[1][cs] + part[2][cs] + part[3][cs] + bs0;
            outp[(long)b * TT * CC + (long)e * CC + cs] = cum0;
            if (cs < CC - 64) {
                cum1 += part[0][64 + cs] + part[1][64 + cs] + part[2][64 + cs] +
                        part[3][64 + cs] + bs1;
                outp[(long)b * TT * CC + (long)e * CC + 64 + cs] = cum1;
            }
        }
        __syncthreads();
    }
}

// ---------------------------------------------------------------------------
extern "C" void kernel_launch(void* const* d_in, const int* in_sizes, int n_in,
                              void* d_out, int out_size, void* d_ws, size_t ws_size,
                              hipStream_t stream)
{
    const float* x    = (const float*)d_in[0];
    const float* Wih0 = (const float*)d_in[1];
    const float* Whh0 = (const float*)d_in[2];
    const float* bih0 = (const float*)d_in[3];
    const float* bhh0 = (const float*)d_in[4];
    const float* Wih1 = (const float*)d_in[5];
    const float* Whh1 = (const float*)d_in[6];
    const float* bih1 = (const float*)d_in[7];
    const float* bhh1 = (const float*)d_in[8];
    const float* Wt   = (const float*)d_in[9];
    const float* bt   = (const float*)d_in[10];
    const float* Ws   = (const float*)d_in[11];
    const float* bs   = (const float*)d_in[12];
    float* outp = (float*)d_out;

    char* p = (char*)d_ws;
    auto alloc = [&](size_t bytes) -> char* {
        char* r = p; p += (bytes + 255) & ~(size_t)255; return r;
    };
    u16* h0b = (u16*)alloc(2L * HS * 2);
    u16* h1b = (u16*)alloc(2L * HS * 2);
    u16* xbf = (u16*)alloc((size_t)BB * TT * CPAD * 2);
    u16* wi0 = (u16*)alloc((size_t)NGATE * CPAD * 2);
    u16* wh0 = (u16*)alloc((size_t)NGATE * SS * 2);
    u16* wi1 = (u16*)alloc((size_t)NGATE * SS * 2);
    u16* wh1 = (u16*)alloc((size_t)NGATE * SS * 2);
    u16* Mbf = (u16*)alloc((size_t)NGATE * SS * 2);
    float* c0vec = (float*)alloc((size_t)NGATE * 4);
    float* gi0i  = (float*)alloc((size_t)BB * NGATE * 4);
    u16* temps = (u16*)alloc((size_t)TT * HS * 2);
    int* arrive = (int*)alloc((size_t)NBLK * 16 * 4);
    int* ep = (int*)alloc(256);

    hipMemsetAsync(h0b, 0, 2L * HS * 2, stream);
    hipMemsetAsync(h1b, 0, 2L * HS * 2, stream);
    hipMemsetAsync(arrive, 0, (size_t)NBLK * 16 * 4, stream);
    hipMemsetAsync(ep, 0, 256, stream);

    prep1_kernel<<<1024, 256, 0, stream>>>(x, Wih0, Whh0, Wih1, Whh1,
                                           xbf, wi0, wh0, wi1, wh1);
    prep2_kernel<<<1024, 256, 0, stream>>>(x, Wih0, Ws, bs, Mbf, c0vec, gi0i);

    persist_kernel<<<NBLK, 256, 0, stream>>>(
        xbf, wi0, wh0, wi1, wh1, Mbf, bih0, bhh0, bih1, bhh1,
        c0vec, gi0i, Wt, bt, h0b, h1b, temps, arrive, ep);

    frames_kernel<<<BB, 256, 0, stream>>>(temps, x, Ws, bs, outp);
}

// Round 4
// 4928.941 us; speedup vs baseline: 2.0058x; 1.5655x over previous
//
#include <hip/hip_runtime.h>
#include <stdint.h>

typedef unsigned short u16;
typedef uint32_t u32;
typedef __attribute__((ext_vector_type(8))) short short8;
typedef __attribute__((ext_vector_type(4))) float floatx4;

constexpr int BB = 128;     // batch
constexpr int TT = 64;      // time steps
constexpr int CC = 66;      // frame channels
constexpr int CPAD = 96;    // C padded to multiple of 32 (MFMA K-chunk)
constexpr int SS = 512;     // hidden
constexpr int NGATE = 1536; // 3*S
constexpr int NBLK = 128;   // persistent blocks (<=256 CUs -> co-resident)
constexpr int HS = BB * SS;

__device__ __forceinline__ u16 f2bf(float f) {
    u32 u = __float_as_uint(f);
    u32 r = (u + 0x7fffu + ((u >> 16) & 1u)) >> 16;
    return (u16)r;
}
__device__ __forceinline__ float bf2f(u16 h) {
    return __uint_as_float(((u32)h) << 16);
}
__device__ __forceinline__ float sigm(float x) { return 1.f / (1.f + __expf(-x)); }
__device__ __forceinline__ float tanh_f(float x) { return 1.f - 2.f / (1.f + __expf(2.f * x)); }

// ---- coherence-bypass primitives (MALL-coherent, no cache maintenance) ----
__device__ __forceinline__ void store_u16_cc(u16* p, u16 v) {
    asm volatile("global_store_short %0, %1, off sc0 sc1"
                 :: "v"(p), "v"((u32)v) : "memory");
}
__device__ __forceinline__ void load_issue_cc(const u16* p, short8& d) {
    asm volatile("global_load_dwordx4 %0, %1, off sc0 sc1"
                 : "=v"(d) : "v"(p));
}
__device__ __forceinline__ void vm_drain() {
    asm volatile("s_waitcnt vmcnt(0)" ::: "memory");
}

// ---------------------------------------------------------------------------
// prep1: bf16 conversion of x (padded to 96) and the 4 GRU weight matrices.
// ---------------------------------------------------------------------------
__global__ void prep1_kernel(const float* __restrict__ x,
                             const float* __restrict__ Wih0,
                             const float* __restrict__ Whh0,
                             const float* __restrict__ Wih1,
                             const float* __restrict__ Whh1,
                             u16* __restrict__ xbf, u16* __restrict__ wi0,
                             u16* __restrict__ wh0, u16* __restrict__ wi1,
                             u16* __restrict__ wh1)
{
    const int N_xbf = BB * TT * CPAD;
    const int N_wi0 = NGATE * CPAD;
    const int N_whh = NGATE * SS;
    const long total = (long)N_xbf + N_wi0 + 3L * N_whh;
    for (long i = (long)blockIdx.x * blockDim.x + threadIdx.x; i < total;
         i += (long)gridDim.x * blockDim.x) {
        long idx = i;
        if (idx < N_xbf) {
            int c = idx % CPAD; int bt = idx / CPAD;
            float v = (c < CC) ? x[(long)bt * CC + c] : 0.f;
            xbf[idx] = f2bf(v); continue;
        }
        idx -= N_xbf;
        if (idx < N_wi0) {
            int c = idx % CPAD; int n = idx / CPAD;
            float v = (c < CC) ? Wih0[(long)n * CC + c] : 0.f;
            wi0[idx] = f2bf(v); continue;
        }
        idx -= N_wi0;
        if (idx < N_whh) { wh0[idx] = f2bf(Whh0[idx]); continue; }
        idx -= N_whh;
        if (idx < N_whh) { wi1[idx] = f2bf(Wih1[idx]); continue; }
        idx -= N_whh;
        wh1[idx] = f2bf(Whh1[idx]);
    }
}

// ---------------------------------------------------------------------------
// prep2: M = Wih0[:, :66] @ Ws (bf16); c0vec = Wih0 @ bs; gi0i = x_last@Wih0^T
// ---------------------------------------------------------------------------
__global__ void prep2_kernel(const float* __restrict__ x,
                             const float* __restrict__ Wih0,
                             const float* __restrict__ Ws,
                             const float* __restrict__ bs,
                             u16* __restrict__ Mbf, float* __restrict__ c0vec,
                             float* __restrict__ gi0i)
{
    const long NM = (long)NGATE * SS;
    const long NC = NGATE;
    const long NG = (long)BB * NGATE;
    const long total = NM + NC + NG;
    for (long i = (long)blockIdx.x * blockDim.x + threadIdx.x; i < total;
         i += (long)gridDim.x * blockDim.x) {
        long idx = i;
        if (idx < NM) {
            int s = idx % SS; int g = idx / SS;
            float acc = 0.f;
            for (int c = 0; c < CC; ++c)
                acc += Wih0[(long)g * CC + c] * Ws[(long)c * SS + s];
            Mbf[idx] = f2bf(acc); continue;
        }
        idx -= NM;
        if (idx < NC) {
            int g = idx;
            float acc = 0.f;
            for (int c = 0; c < CC; ++c) acc += Wih0[(long)g * CC + c] * bs[c];
            c0vec[g] = acc; continue;
        }
        idx -= NC;
        {
            int g = idx % NGATE; int b = idx / NGATE;
            float acc = 0.f;
            const float* xl = x + ((long)b * TT + (TT - 1)) * CC;
            for (int c = 0; c < CC; ++c) acc += xl[c] * Wih0[(long)g * CC + c];
            gi0i[idx] = acc;
        }
    }
}

// ---------------------------------------------------------------------------
// Fence-free grid barrier.  Data ordering: every wave drains its sc0sc1
// stores (vm_drain) BEFORE __syncthreads, so all block data is at the
// coherence point before thread 0 publishes arrival.  Flags use relaxed
// agent-scope atomics (proven device-coherent in round 3).  NO cache
// maintenance instructions anywhere.
// ---------------------------------------------------------------------------
__device__ __forceinline__ void gbar(int* __restrict__ arrive,
                                     int* __restrict__ ep, int target) {
    vm_drain();
    __syncthreads();
    if (blockIdx.x == 0) {
        if (threadIdx.x < 64) {
            const int lane = threadIdx.x;
            if (lane == 0)
                __hip_atomic_store(&arrive[0], target, __ATOMIC_RELAXED,
                                   __HIP_MEMORY_SCOPE_AGENT);
            for (;;) {
                int v0 = __hip_atomic_load(&arrive[lane * 16], __ATOMIC_RELAXED,
                                           __HIP_MEMORY_SCOPE_AGENT);
                int v1 = __hip_atomic_load(&arrive[(lane + 64) * 16],
                                           __ATOMIC_RELAXED,
                                           __HIP_MEMORY_SCOPE_AGENT);
                if (__all(v0 >= target && v1 >= target)) break;
                __builtin_amdgcn_s_sleep(1);
            }
            if (lane == 0)
                __hip_atomic_store(ep, target, __ATOMIC_RELAXED,
                                   __HIP_MEMORY_SCOPE_AGENT);
        }
        __syncthreads();
    } else {
        if (threadIdx.x == 0) {
            __hip_atomic_store(&arrive[blockIdx.x * 16], target,
                               __ATOMIC_RELAXED, __HIP_MEMORY_SCOPE_AGENT);
            while (__hip_atomic_load(ep, __ATOMIC_RELAXED,
                                     __HIP_MEMORY_SCOPE_AGENT) < target)
                __builtin_amdgcn_s_sleep(1);
        }
        __syncthreads();
    }
}

// ---------------------------------------------------------------------------
// Stage a 32-row x 512-col bf16 slab (h-state) from coherent global into LDS.
// 256 threads x 8 chunks of 16B, all loads in flight at once (one MALL RTT).
// XOR swizzle (chunk ^ (row&7)) kills LDS bank conflicts for the MFMA reads.
// ---------------------------------------------------------------------------
__device__ __forceinline__ void stage_issue(const u16* __restrict__ g,
                                            short8* v) {
    int c = threadIdx.x;
#pragma unroll
    for (int i = 0; i < 8; ++i, c += 256) {
        const u16* src = g + ((c >> 6) << 9) + ((c & 63) << 3);
        load_issue_cc(src, v[i]);
    }
}
__device__ __forceinline__ void stage_commit(u16* __restrict__ slab,
                                             const short8* v) {
    int c = threadIdx.x;
#pragma unroll
    for (int i = 0; i < 8; ++i, c += 256) {
        int row = c >> 6, ch = c & 63;
        *(volatile short8*)(slab + (row << 9) + (((ch ^ (row & 7))) << 3)) = v[i];
    }
}

// ---------------------------------------------------------------------------
// Triple-gate MFMA over K=512 with A from the swizzled LDS slab.
// ---------------------------------------------------------------------------
#define MFMA_BF16(a, wp, acc) \
    acc = __builtin_amdgcn_mfma_f32_16x16x32_bf16(a, *(const short8*)(wp), acc, 0, 0, 0)

__device__ __forceinline__ void mm3_lds(const u16* __restrict__ slab, int row,
                                        int quad,
                                        const u16* __restrict__ w0,
                                        const u16* __restrict__ w1,
                                        const u16* __restrict__ w2,
                                        floatx4& A0, floatx4& A1, floatx4& A2) {
    const u16* base = slab + (row << 9);
    const int sw = row & 7;
#pragma unroll
    for (int kc = 0; kc < 16; ++kc) {
        short8 a = *(const short8*)(base + ((((kc << 2) + quad) ^ sw) << 3));
        const int k = kc << 5;
        MFMA_BF16(a, w0 + k, A0);
        MFMA_BF16(a, w1 + k, A1);
        MFMA_BF16(a, w2 + k, A2);
    }
}

// Triple-gate MFMA with A direct from (read-only, cached) global memory.
template <int K>
__device__ __forceinline__ void mm3_g(const u16* __restrict__ aP,
                                      const u16* __restrict__ w0,
                                      const u16* __restrict__ w1,
                                      const u16* __restrict__ w2,
                                      floatx4& A0, floatx4& A1, floatx4& A2) {
#pragma unroll
    for (int k = 0; k < K; k += 32) {
        short8 a = *(const short8*)(aP + k);
        MFMA_BF16(a, w0 + k, A0);
        MFMA_BF16(a, w1 + k, A1);
        MFMA_BF16(a, w2 + k, A2);
    }
}

// ---------------------------------------------------------------------------
// Persistent kernel.  Blocks 0..63 = L0 tiles (32b x 32s), 64..127 = L1.
// Read-only weights: normal cached loads (L2 stays warm forever - no fences).
// h0/h1/temps: sc0sc1 stores + LDS staging via sc0sc1 loads.
// Sliding window + temporal conv: register-resident (4 x 16 packed u32).
// ---------------------------------------------------------------------------
__global__ __launch_bounds__(256, 1) void persist_kernel(
    const u16* __restrict__ xbf,
    const u16* __restrict__ wi0, const u16* __restrict__ wh0,
    const u16* __restrict__ wi1, const u16* __restrict__ wh1,
    const u16* __restrict__ Mbf,
    const float* __restrict__ bih0, const float* __restrict__ bhh0,
    const float* __restrict__ bih1, const float* __restrict__ bhh1,
    const float* __restrict__ c0vec, const float* __restrict__ gi0i,
    const float* __restrict__ Wt, const float* __restrict__ bt,
    u16* __restrict__ h0b, u16* __restrict__ h1b,      // 2 buffers each
    u16* __restrict__ temps,                           // [64][128][512] bf16
    int* __restrict__ arrive, int* __restrict__ ep)
{
    __shared__ u16 slabA[32 * 512];   // 32 KB
    __shared__ u16 slabB[32 * 512];   // 32 KB

    const int tid = threadIdx.x;
    const int wave = tid >> 6, lane = tid & 63;
    const int msub = wave & 1, ssub = wave >> 1;
    const int l15 = lane & 15, quad = lane >> 4;
    const bool isL0 = blockIdx.x < 64;
    const int blk2 = isL0 ? blockIdx.x : blockIdx.x - 64;
    const int b0blk = (blk2 & 3) * 32;          // block's 32-batch base
    const int b0 = b0blk + msub * 16;           // wave's 16-batch base
    const int s0 = (blk2 >> 2) * 32 + ssub * 16;
    const int s = s0 + l15;
    const int arow = msub * 16 + l15;           // A-row within slab

    // ---- per-thread constants & register state ----
    float bir, biz, bin, bhn;
    float c0r = 0.f, c0z = 0.f, c0n = 0.f;
    float hf[4] = {0.f, 0.f, 0.f, 0.f};
    float gi[12];
    float wt[32]; float btv = 0.f;
    u32 wreg[4][16];                 // register sliding window (bf16 pairs)
#pragma unroll
    for (int r = 0; r < 4; ++r)
#pragma unroll
        for (int i = 0; i < 16; ++i) wreg[r][i] = 0u;

    if (isL0) {
        bir = bih0[s] + bhh0[s];
        biz = bih0[512 + s] + bhh0[512 + s];
        bin = bih0[1024 + s];
        bhn = bhh0[1024 + s];
        c0r = c0vec[s]; c0z = c0vec[512 + s]; c0n = c0vec[1024 + s];
#pragma unroll
        for (int g = 0; g < 3; ++g)
#pragma unroll
            for (int r = 0; r < 4; ++r)
                gi[g * 4 + r] = gi0i[(long)(b0 + quad * 4 + r) * NGATE + g * 512 + s];
    } else {
        bir = bih1[s] + bhh1[s];
        biz = bih1[512 + s] + bhh1[512 + s];
        bin = bih1[1024 + s];
        bhn = bhh1[1024 + s];
#pragma unroll
        for (int j = 0; j < 32; ++j) wt[j] = Wt[j];
        btv = bt[0];
    }

    const u16 *wiR, *wiZ, *wiN, *whR, *whZ, *whN, *mR, *mZ, *mN;
    if (isL0) {
        wiR = wi0 + (long)s * CPAD + quad * 8;
        wiZ = wi0 + (long)(512 + s) * CPAD + quad * 8;
        wiN = wi0 + (long)(1024 + s) * CPAD + quad * 8;
        whR = wh0 + (long)s * SS + quad * 8;
        whZ = wh0 + (long)(512 + s) * SS + quad * 8;
        whN = wh0 + (long)(1024 + s) * SS + quad * 8;
        mR = Mbf + (long)s * SS + quad * 8;
        mZ = Mbf + (long)(512 + s) * SS + quad * 8;
        mN = Mbf + (long)(1024 + s) * SS + quad * 8;
    } else {
        wiR = wi1 + (long)s * SS + quad * 8;
        wiZ = wi1 + (long)(512 + s) * SS + quad * 8;
        wiN = wi1 + (long)(1024 + s) * SS + quad * 8;
        whR = wh1 + (long)s * SS + quad * 8;
        whZ = wh1 + (long)(512 + s) * SS + quad * 8;
        whN = wh1 + (long)(1024 + s) * SS + quad * 8;
        mR = mZ = mN = nullptr;
    }

    short8 stv[16];
    int c0p = 0, c1p = 0, bar = 0;

    // ================= encoder: phases p = 0..63 =================
    for (int p = 0; p < 64; ++p) {
        const bool act0 = isL0 && (p < 63);
        const bool act1 = (!isL0) && (p >= 1);
        if (act0) {
            stage_issue(h0b + (long)c0p * HS + (long)b0blk * SS, stv);
            vm_drain();
            stage_commit(slabA, stv);
        } else if (act1) {
            stage_issue(h0b + (long)c0p * HS + (long)b0blk * SS, stv);
            stage_issue(h1b + (long)c1p * HS + (long)b0blk * SS, stv + 8);
            vm_drain();
            stage_commit(slabA, stv);
            stage_commit(slabB, stv + 8);
        }
        __syncthreads();

        if (act0) {
            floatx4 aR = {0,0,0,0}, aZ = aR, aNI = aR, aNH = aR;
            const u16* aP = xbf + ((long)(b0 + l15) * TT + p) * CPAD + quad * 8;
            mm3_g<CPAD>(aP, wiR, wiZ, wiN, aR, aZ, aNI);
            mm3_lds(slabA, arow, quad, whR, whZ, whN, aR, aZ, aNH);
            u16* hN = h0b + (long)(1 - c0p) * HS;
#pragma unroll
            for (int r = 0; r < 4; ++r) {
                float rr = sigm(aR[r] + bir);
                float zz = sigm(aZ[r] + biz);
                float nn = tanh_f(aNI[r] + bin + rr * (aNH[r] + bhn));
                float hv = (1.f - zz) * nn + zz * hf[r];
                hf[r] = hv;
                store_u16_cc(hN + (long)(b0 + quad * 4 + r) * SS + s, f2bf(hv));
            }
        } else if (act1) {
            floatx4 aR = {0,0,0,0}, aZ = aR, aNI = aR, aNH = aR;
            mm3_lds(slabA, arow, quad, wiR, wiZ, wiN, aR, aZ, aNI);
            mm3_lds(slabB, arow, quad, whR, whZ, whN, aR, aZ, aNH);
            u16* hN = h1b + (long)(1 - c1p) * HS;
#pragma unroll
            for (int r = 0; r < 4; ++r) {
                float rr = sigm(aR[r] + bir);
                float zz = sigm(aZ[r] + biz);
                float nn = tanh_f(aNI[r] + bin + rr * (aNH[r] + bhn));
                float hv = (1.f - zz) * nn + zz * hf[r];
                hf[r] = hv;
                u16 hb = f2bf(hv);
                store_u16_cc(hN + (long)(b0 + quad * 4 + r) * SS + s, hb);
                // shift register window, insert newest at position 31
#pragma unroll
                for (int i = 0; i < 15; ++i)
                    wreg[r][i] = (wreg[r][i] >> 16) | (wreg[r][i + 1] << 16);
                wreg[r][15] = (wreg[r][15] >> 16) | ((u32)hb << 16);
            }
        }
        gbar(arrive, ep, ++bar);
        if (p < 63) c0p ^= 1;
        if (p >= 1) c1p ^= 1;
    }

    // ================= decoder: d = 0..63, 2 phases each =================
    for (int d = 0; d < 64; ++d) {
        // ---- phase A: layer 0 (blocks 0..63) ----
        if (isL0) {
            if (d > 0)
                stage_issue(temps + (long)(d - 1) * HS + (long)b0blk * SS, stv);
            stage_issue(h0b + (long)c0p * HS + (long)b0blk * SS, stv + 8);
            vm_drain();
            if (d > 0) stage_commit(slabA, stv);
            stage_commit(slabB, stv + 8);
            __syncthreads();

            if (d > 0) {   // gi(d) = gi(d-1) + M @ temp(d-1) + c0
                floatx4 tR = {0,0,0,0}, tZ = tR, tN = tR;
                mm3_lds(slabA, arow, quad, mR, mZ, mN, tR, tZ, tN);
#pragma unroll
                for (int r = 0; r < 4; ++r) {
                    gi[r] += tR[r] + c0r;
                    gi[4 + r] += tZ[r] + c0z;
                    gi[8 + r] += tN[r] + c0n;
                }
            }
            floatx4 hR = {0,0,0,0}, hZ = hR, hN4 = hR;
            mm3_lds(slabB, arow, quad, whR, whZ, whN, hR, hZ, hN4);
            u16* hN = h0b + (long)(1 - c0p) * HS;
#pragma unroll
            for (int r = 0; r < 4; ++r) {
                float rr = sigm(gi[r] + hR[r] + bir);
                float zz = sigm(gi[4 + r] + hZ[r] + biz);
                float nn = tanh_f(gi[8 + r] + bin + rr * (hN4[r] + bhn));
                float hv = (1.f - zz) * nn + zz * hf[r];
                hf[r] = hv;
                store_u16_cc(hN + (long)(b0 + quad * 4 + r) * SS + s, f2bf(hv));
            }
        }
        gbar(arrive, ep, ++bar);
        c0p ^= 1;

        // ---- phase B: layer 1 + window/temp (blocks 64..127) ----
        if (!isL0) {
            stage_issue(h0b + (long)c0p * HS + (long)b0blk * SS, stv);
            stage_issue(h1b + (long)c1p * HS + (long)b0blk * SS, stv + 8);
            vm_drain();
            stage_commit(slabA, stv);
            stage_commit(slabB, stv + 8);
            __syncthreads();

            floatx4 aR = {0,0,0,0}, aZ = aR, aNI = aR, aNH = aR;
            mm3_lds(slabA, arow, quad, wiR, wiZ, wiN, aR, aZ, aNI);
            mm3_lds(slabB, arow, quad, whR, whZ, whN, aR, aZ, aNH);
            u16* hN = h1b + (long)(1 - c1p) * HS;
            u16* tOut = temps + (long)d * HS;
#pragma unroll
            for (int r = 0; r < 4; ++r) {
                float rr = sigm(aR[r] + bir);
                float zz = sigm(aZ[r] + biz);
                float nn = tanh_f(aNI[r] + bin + rr * (aNH[r] + bhn));
                float hv = (1.f - zz) * nn + zz * hf[r];
                hf[r] = hv;
                u16 hb = f2bf(hv);
                const int b = b0 + quad * 4 + r;
                store_u16_cc(hN + (long)b * SS + s, hb);
                // shift window, insert newest
#pragma unroll
                for (int i = 0; i < 15; ++i)
                    wreg[r][i] = (wreg[r][i] >> 16) | (wreg[r][i + 1] << 16);
                wreg[r][15] = (wreg[r][15] >> 16) | ((u32)hb << 16);
                // temporal conv: positions 0..31 = h1(d-31..d) vs Wt[0..31]
                float tacc = btv;
#pragma unroll
                for (int i = 0; i < 16; ++i) {
                    u32 wv = wreg[r][i];
                    tacc += __uint_as_float(wv << 16) * wt[2 * i];
                    tacc += __uint_as_float(wv & 0xffff0000u) * wt[2 * i + 1];
                }
                store_u16_cc(tOut + (long)b * SS + s, f2bf(tacc));
            }
        }
        gbar(arrive, ep, ++bar);
        c1p ^= 1;
    }
}

// ---------------------------------------------------------------------------
// frames epilogue (parallel): frames[b][e][c] = x_last[b][c]
//      + sum_{e'<=e} ( temp(e') @ Ws^T + bs )[c]
// ---------------------------------------------------------------------------
__global__ __launch_bounds__(256) void frames_kernel(
    const u16* __restrict__ temps, const float* __restrict__ x,
    const float* __restrict__ Ws, const float* __restrict__ bs,
    float* __restrict__ outp)
{
    const int b = blockIdx.x, tid = threadIdx.x;
    const int sc = tid >> 6, cs = tid & 63;
    __shared__ float part[4][128];
    float cum0 = x[((long)b * TT + (TT - 1)) * CC + cs];
    float cum1 = (cs < CC - 64) ? x[((long)b * TT + (TT - 1)) * CC + 64 + cs] : 0.f;
    const float bs0 = bs[cs];
    const float bs1 = (cs < CC - 64) ? bs[64 + cs] : 0.f;
    for (int e = 0; e < TT; ++e) {
        const u16* tr = temps + (long)e * HS + (long)b * SS + sc * 128;
        float p0 = 0.f, p1 = 0.f;
        for (int i = 0; i < 128; ++i) {
            float tv = bf2f(tr[i]);
            p0 += tv * Ws[(long)cs * SS + sc * 128 + i];
            if (cs < CC - 64) p1 += tv * Ws[(long)(64 + cs) * SS + sc * 128 + i];
        }
        part[sc][cs] = p0;
        part[sc][64 + cs] = p1;
        __syncthreads();
        if (sc == 0) {
            cum0 += part[0][cs] + part[1][cs] + part[2][cs] + part[3][cs] + bs0;
            outp[(long)b * TT * CC + (long)e * CC + cs] = cum0;
            if (cs < CC - 64) {
                cum1 += part[0][64 + cs] + part[1][64 + cs] + part[2][64 + cs] +
                        part[3][64 + cs] + bs1;
                outp[(long)b * TT * CC + (long)e * CC + 64 + cs] = cum1;
            }
        }
        __syncthreads();
    }
}

// ---------------------------------------------------------------------------
extern "C" void kernel_launch(void* const* d_in, const int* in_sizes, int n_in,
                              void* d_out, int out_size, void* d_ws, size_t ws_size,
                              hipStream_t stream)
{
    const float* x    = (const float*)d_in[0];
    const float* Wih0 = (const float*)d_in[1];
    const float* Whh0 = (const float*)d_in[2];
    const float* bih0 = (const float*)d_in[3];
    const float* bhh0 = (const float*)d_in[4];
    const float* Wih1 = (const float*)d_in[5];
    const float* Whh1 = (const float*)d_in[6];
    const float* bih1 = (const float*)d_in[7];
    const float* bhh1 = (const float*)d_in[8];
    const float* Wt   = (const float*)d_in[9];
    const float* bt   = (const float*)d_in[10];
    const float* Ws   = (const float*)d_in[11];
    const float* bs   = (const float*)d_in[12];
    float* outp = (float*)d_out;

    char* p = (char*)d_ws;
    auto alloc = [&](size_t bytes) -> char* {
        char* r = p; p += (bytes + 255) & ~(size_t)255; return r;
    };
    u16* h0b = (u16*)alloc(2L * HS * 2);
    u16* h1b = (u16*)alloc(2L * HS * 2);
    u16* xbf = (u16*)alloc((size_t)BB * TT * CPAD * 2);
    u16* wi0 = (u16*)alloc((size_t)NGATE * CPAD * 2);
    u16* wh0 = (u16*)alloc((size_t)NGATE * SS * 2);
    u16* wi1 = (u16*)alloc((size_t)NGATE * SS * 2);
    u16* wh1 = (u16*)alloc((size_t)NGATE * SS * 2);
    u16* Mbf = (u16*)alloc((size_t)NGATE * SS * 2);
    float* c0vec = (float*)alloc((size_t)NGATE * 4);
    float* gi0i  = (float*)alloc((size_t)BB * NGATE * 4);
    u16* temps = (u16*)alloc((size_t)TT * HS * 2);
    int* arrive = (int*)alloc((size_t)NBLK * 16 * 4);
    int* ep = (int*)alloc(256);

    hipMemsetAsync(h0b, 0, 2L * HS * 2, stream);
    hipMemsetAsync(h1b, 0, 2L * HS * 2, stream);
    hipMemsetAsync(arrive, 0, (size_t)NBLK * 16 * 4, stream);
    hipMemsetAsync(ep, 0, 256, stream);

    prep1_kernel<<<1024, 256, 0, stream>>>(x, Wih0, Whh0, Wih1, Whh1,
                                           xbf, wi0, wh0, wi1, wh1);
    prep2_kernel<<<1024, 256, 0, stream>>>(x, Wih0, Ws, bs, Mbf, c0vec, gi0i);

    persist_kernel<<<NBLK, 256, 0, stream>>>(
        xbf, wi0, wh0, wi1, wh1, Mbf, bih0, bhh0, bih1, bhh1,
        c0vec, gi0i, Wt, bt, h0b, h1b, temps, arrive, ep);

    frames_kernel<<<BB, 256, 0, stream>>>(temps, x, Ws, bs, outp);
}

// Round 5
// 4479.841 us; speedup vs baseline: 2.2068x; 1.1002x over previous
//
#include <hip/hip_runtime.h>
#include <stdint.h>

typedef unsigned short u16;
typedef uint32_t u32;
typedef __attribute__((ext_vector_type(8))) short short8;
typedef __attribute__((ext_vector_type(4))) float floatx4;

constexpr int BB = 128;     // batch
constexpr int TT = 64;      // time steps
constexpr int CC = 66;      // frame channels
constexpr int CPAD = 96;    // C padded to multiple of 32 (MFMA K-chunk)
constexpr int SS = 512;     // hidden
constexpr int NGATE = 1536; // 3*S
constexpr int NGRP = 8;     // independent batch groups (16 batches each)
constexpr int GBLK = 16;    // blocks per group (s-split by 32)
constexpr int GS = 16 * SS; // per-group state slab elements (16 x 512)

__device__ __forceinline__ u16 f2bf(float f) {
    u32 u = __float_as_uint(f);
    u32 r = (u + 0x7fffu + ((u >> 16) & 1u)) >> 16;
    return (u16)r;
}
__device__ __forceinline__ float bf2f(u16 h) {
    return __uint_as_float(((u32)h) << 16);
}
__device__ __forceinline__ float sigm(float x) { return 1.f / (1.f + __expf(-x)); }
__device__ __forceinline__ float tanh_f(float x) { return 1.f - 2.f / (1.f + __expf(2.f * x)); }

// ---- coherence-bypass primitives (MALL-coherent, no cache maintenance) ----
__device__ __forceinline__ void store_u16_cc(u16* p, u16 v) {
    asm volatile("global_store_short %0, %1, off sc0 sc1"
                 :: "v"(p), "v"((u32)v) : "memory");
}
__device__ __forceinline__ void load_issue_cc(const u16* p, short8& d) {
    asm volatile("global_load_dwordx4 %0, %1, off sc0 sc1"
                 : "=v"(d) : "v"(p));
}
__device__ __forceinline__ void vm_drain() {
    asm volatile("s_waitcnt vmcnt(0)" ::: "memory");
}

// ---------------------------------------------------------------------------
// prep1: bf16 conversion of x (padded to 96) and the 4 GRU weight matrices.
// ---------------------------------------------------------------------------
__global__ void prep1_kernel(const float* __restrict__ x,
                             const float* __restrict__ Wih0,
                             const float* __restrict__ Whh0,
                             const float* __restrict__ Wih1,
                             const float* __restrict__ Whh1,
                             u16* __restrict__ xbf, u16* __restrict__ wi0,
                             u16* __restrict__ wh0, u16* __restrict__ wi1,
                             u16* __restrict__ wh1)
{
    const int N_xbf = BB * TT * CPAD;
    const int N_wi0 = NGATE * CPAD;
    const int N_whh = NGATE * SS;
    const long total = (long)N_xbf + N_wi0 + 3L * N_whh;
    for (long i = (long)blockIdx.x * blockDim.x + threadIdx.x; i < total;
         i += (long)gridDim.x * blockDim.x) {
        long idx = i;
        if (idx < N_xbf) {
            int c = idx % CPAD; int bt = idx / CPAD;
            float v = (c < CC) ? x[(long)bt * CC + c] : 0.f;
            xbf[idx] = f2bf(v); continue;
        }
        idx -= N_xbf;
        if (idx < N_wi0) {
            int c = idx % CPAD; int n = idx / CPAD;
            float v = (c < CC) ? Wih0[(long)n * CC + c] : 0.f;
            wi0[idx] = f2bf(v); continue;
        }
        idx -= N_wi0;
        if (idx < N_whh) { wh0[idx] = f2bf(Whh0[idx]); continue; }
        idx -= N_whh;
        if (idx < N_whh) { wi1[idx] = f2bf(Wih1[idx]); continue; }
        idx -= N_whh;
        wh1[idx] = f2bf(Whh1[idx]);
    }
}

// ---------------------------------------------------------------------------
// prep2: M = Wih0[:, :66] @ Ws (bf16); c0vec = Wih0 @ bs; gi0i = x_last@Wih0^T
// ---------------------------------------------------------------------------
__global__ void prep2_kernel(const float* __restrict__ x,
                             const float* __restrict__ Wih0,
                             const float* __restrict__ Ws,
                             const float* __restrict__ bs,
                             u16* __restrict__ Mbf, float* __restrict__ c0vec,
                             float* __restrict__ gi0i)
{
    const long NM = (long)NGATE * SS;
    const long NC = NGATE;
    const long NG = (long)BB * NGATE;
    const long total = NM + NC + NG;
    for (long i = (long)blockIdx.x * blockDim.x + threadIdx.x; i < total;
         i += (long)gridDim.x * blockDim.x) {
        long idx = i;
        if (idx < NM) {
            int s = idx % SS; int g = idx / SS;
            float acc = 0.f;
            for (int c = 0; c < CC; ++c)
                acc += Wih0[(long)g * CC + c] * Ws[(long)c * SS + s];
            Mbf[idx] = f2bf(acc); continue;
        }
        idx -= NM;
        if (idx < NC) {
            int g = idx;
            float acc = 0.f;
            for (int c = 0; c < CC; ++c) acc += Wih0[(long)g * CC + c] * bs[c];
            c0vec[g] = acc; continue;
        }
        idx -= NC;
        {
            int g = idx % NGATE; int b = idx / NGATE;
            float acc = 0.f;
            const float* xl = x + ((long)b * TT + (TT - 1)) * CC;
            for (int c = 0; c < CC; ++c) acc += xl[c] * Wih0[(long)g * CC + c];
            gi0i[idx] = acc;
        }
    }
}

// ---------------------------------------------------------------------------
// Group barrier (16 blocks, symmetric, no leader): after vm_drain +
// __syncthreads, thread 0 publishes its monotone phase counter to its own
// cacheline-isolated flag; wave 0's lanes 0..15 poll all 16 flags directly.
// Two MALL RTTs total; no ep indirection, no contended RMW, no fences.
// ---------------------------------------------------------------------------
__device__ __forceinline__ void group_bar(int* __restrict__ gf, int rank,
                                          int target) {
    vm_drain();
    __syncthreads();
    if (threadIdx.x < 64) {
        const int lane = threadIdx.x;
        if (lane == 0)
            __hip_atomic_store(gf + rank * 16, target, __ATOMIC_RELAXED,
                               __HIP_MEMORY_SCOPE_AGENT);
        for (;;) {
            int v = 0x7fffffff;
            if (lane < GBLK)
                v = __hip_atomic_load(gf + lane * 16, __ATOMIC_RELAXED,
                                      __HIP_MEMORY_SCOPE_AGENT);
            if (__all(v >= target)) break;
            __builtin_amdgcn_s_sleep(1);
        }
    }
    __syncthreads();
}

// ---------------------------------------------------------------------------
// Stage one 16-row x 512-col bf16 slab from coherent global into LDS.
// 1024 16B-chunks / 256 threads = 4 concurrent loads each (one MALL RTT).
// XOR swizzle (chunk ^ (row&7)) keeps the MFMA A-reads conflict-cheap.
// ---------------------------------------------------------------------------
__device__ __forceinline__ void stage_issue(const u16* __restrict__ g,
                                            short8* v) {
    int c = threadIdx.x;
#pragma unroll
    for (int i = 0; i < 4; ++i, c += 256) {
        const u16* src = g + ((c >> 6) << 9) + ((c & 63) << 3);
        load_issue_cc(src, v[i]);
    }
}
__device__ __forceinline__ void stage_commit(u16* __restrict__ slab,
                                             const short8* v) {
    int c = threadIdx.x;
#pragma unroll
    for (int i = 0; i < 4; ++i, c += 256) {
        int row = c >> 6, ch = c & 63;
        *(volatile short8*)(slab + (row << 9) + ((ch ^ (row & 7)) << 3)) = v[i];
    }
}

// ---------------------------------------------------------------------------
#define MFMA_BF16(a, wp, acc) \
    acc = __builtin_amdgcn_mfma_f32_16x16x32_bf16(a, *(const short8*)(wp), acc, 0, 0, 0)

// Triple-gate MFMA over K=512, A from swizzled LDS slab (row = lane&15).
__device__ __forceinline__ void mm3_lds(const u16* __restrict__ slab, int row,
                                        int quad,
                                        const u16* __restrict__ w0,
                                        const u16* __restrict__ w1,
                                        const u16* __restrict__ w2,
                                        floatx4& A0, floatx4& A1, floatx4& A2) {
    const u16* base = slab + (row << 9);
    const int sw = row & 7;
#pragma unroll
    for (int kc = 0; kc < 16; ++kc) {
        short8 a = *(const short8*)(base + ((((kc << 2) + quad) ^ sw) << 3));
        const int k = kc << 5;
        MFMA_BF16(a, w0 + k, A0);
        MFMA_BF16(a, w1 + k, A1);
        MFMA_BF16(a, w2 + k, A2);
    }
}

// Triple-gate MFMA, A direct from read-only cached global.
template <int K>
__device__ __forceinline__ void mm3_g(const u16* __restrict__ aP,
                                      const u16* __restrict__ w0,
                                      const u16* __restrict__ w1,
                                      const u16* __restrict__ w2,
                                      floatx4& A0, floatx4& A1, floatx4& A2) {
#pragma unroll
    for (int k = 0; k < K; k += 32) {
        short8 a = *(const short8*)(aP + k);
        MFMA_BF16(a, w0 + k, A0);
        MFMA_BF16(a, w1 + k, A1);
        MFMA_BF16(a, w2 + k, A2);
    }
}

// ---------------------------------------------------------------------------
// Persistent kernel, group-local sync only.
// Group g (blockIdx>>4) owns batches [16g,16g+16); rank (blockIdx&15) owns
// s-slice [32*rank, 32*rank+32).  Waves 0,1 = layer-0 16x16 tiles (s-sub 0/1),
// waves 2,3 = layer-1 tiles.  Per phase: stage 2 slabs (sc0sc1, 1 RTT),
// MFMA, epilogue, slice store, 16-way group barrier.  Weights stay cached.
// ---------------------------------------------------------------------------
__global__ __launch_bounds__(256, 1) void persist_kernel(
    const u16* __restrict__ xbf,
    const u16* __restrict__ wi0, const u16* __restrict__ wh0,
    const u16* __restrict__ wi1, const u16* __restrict__ wh1,
    const u16* __restrict__ Mbf,
    const float* __restrict__ bih0, const float* __restrict__ bhh0,
    const float* __restrict__ bih1, const float* __restrict__ bhh1,
    const float* __restrict__ c0vec, const float* __restrict__ gi0i,
    const float* __restrict__ Wt, const float* __restrict__ bt,
    u16* __restrict__ h0buf,   // [NGRP][2][16][512]
    u16* __restrict__ h1buf,   // [NGRP][2][16][512]
    u16* __restrict__ tstage,  // [NGRP][16][512]
    u16* __restrict__ temps,   // [64][128][512] (cached; read by frames)
    int* __restrict__ gflags)  // [NGRP][16][16]
{
    __shared__ u16 slabA[16 * 512];   // 16 KB
    __shared__ u16 slabB[16 * 512];   // 16 KB

    const int tid = threadIdx.x;
    const int wave = tid >> 6, lane = tid & 63;
    const int l15 = lane & 15, quad = lane >> 4;
    const int grp = blockIdx.x >> 4, rank = blockIdx.x & 15;
    const int b0g = grp * 16;                     // group batch base
    const int ssub = wave & 1;
    const int sg = rank * 32 + ssub * 16 + l15;   // s-coordinate (0..511)
    const bool l0w = wave < 2;                    // layer-0 wave?

    u16* const h0g = h0buf + (long)grp * 2 * GS;
    u16* const h1g = h1buf + (long)grp * 2 * GS;
    u16* const tsg = tstage + (long)grp * GS;
    int* const gf = gflags + grp * GBLK * 16;

    // ---- per-thread constants & register state ----
    float bir, biz, bin, bhn;
    float c0r = 0.f, c0z = 0.f, c0n = 0.f;
    float hf[4] = {0.f, 0.f, 0.f, 0.f};          // own h (L0 or L1 per wave)
    float gi[12];                                 // L0 waves only
    float wt[32]; float btv = 0.f;                // L1 waves only
    u32 wreg[4][16];                              // L1 waves: sliding window
#pragma unroll
    for (int r = 0; r < 4; ++r)
#pragma unroll
        for (int i = 0; i < 16; ++i) wreg[r][i] = 0u;

    if (l0w) {
        bir = bih0[sg] + bhh0[sg];
        biz = bih0[512 + sg] + bhh0[512 + sg];
        bin = bih0[1024 + sg];
        bhn = bhh0[1024 + sg];
        c0r = c0vec[sg]; c0z = c0vec[512 + sg]; c0n = c0vec[1024 + sg];
#pragma unroll
        for (int g3 = 0; g3 < 3; ++g3)
#pragma unroll
            for (int r = 0; r < 4; ++r)
                gi[g3 * 4 + r] =
                    gi0i[(long)(b0g + quad * 4 + r) * NGATE + g3 * 512 + sg];
    } else {
        bir = bih1[sg] + bhh1[sg];
        biz = bih1[512 + sg] + bhh1[512 + sg];
        bin = bih1[1024 + sg];
        bhn = bhh1[1024 + sg];
#pragma unroll
        for (int j = 0; j < 32; ++j) wt[j] = Wt[j];
        btv = bt[0];
    }

    const u16 *wiR, *wiZ, *wiN, *whR, *whZ, *whN, *mR, *mZ, *mN;
    if (l0w) {
        wiR = wi0 + (long)sg * CPAD + quad * 8;
        wiZ = wi0 + (long)(512 + sg) * CPAD + quad * 8;
        wiN = wi0 + (long)(1024 + sg) * CPAD + quad * 8;
        whR = wh0 + (long)sg * SS + quad * 8;
        whZ = wh0 + (long)(512 + sg) * SS + quad * 8;
        whN = wh0 + (long)(1024 + sg) * SS + quad * 8;
        mR = Mbf + (long)sg * SS + quad * 8;
        mZ = Mbf + (long)(512 + sg) * SS + quad * 8;
        mN = Mbf + (long)(1024 + sg) * SS + quad * 8;
    } else {
        wiR = wi1 + (long)sg * SS + quad * 8;
        wiZ = wi1 + (long)(512 + sg) * SS + quad * 8;
        wiN = wi1 + (long)(1024 + sg) * SS + quad * 8;
        whR = wh1 + (long)sg * SS + quad * 8;
        whZ = wh1 + (long)(512 + sg) * SS + quad * 8;
        whN = wh1 + (long)(1024 + sg) * SS + quad * 8;
        mR = mZ = mN = nullptr;
    }

    short8 sv0[4], sv1[4];
    int c0p = 0, c1p = 0, bar = 0;

    // ================= encoder: phases p = 0..63 =================
    for (int p = 0; p < 64; ++p) {
        stage_issue(h0g + (long)c0p * GS, sv0);
        stage_issue(h1g + (long)c1p * GS, sv1);
        vm_drain();
        stage_commit(slabA, sv0);
        stage_commit(slabB, sv1);
        __syncthreads();

        if (l0w) {
            if (p < 63) {
                floatx4 aR = {0,0,0,0}, aZ = aR, aNI = aR, aNH = aR;
                const u16* aP =
                    xbf + ((long)(b0g + l15) * TT + p) * CPAD + quad * 8;
                mm3_g<CPAD>(aP, wiR, wiZ, wiN, aR, aZ, aNI);
                mm3_lds(slabA, l15, quad, whR, whZ, whN, aR, aZ, aNH);
                u16* dst = h0g + (long)(1 - c0p) * GS;
#pragma unroll
                for (int r = 0; r < 4; ++r) {
                    float rr = sigm(aR[r] + bir);
                    float zz = sigm(aZ[r] + biz);
                    float nn = tanh_f(aNI[r] + bin + rr * (aNH[r] + bhn));
                    float hv = (1.f - zz) * nn + zz * hf[r];
                    hf[r] = hv;
                    store_u16_cc(dst + (long)(quad * 4 + r) * SS + sg, f2bf(hv));
                }
            }
        } else {
            if (p >= 1) {
                floatx4 aR = {0,0,0,0}, aZ = aR, aNI = aR, aNH = aR;
                mm3_lds(slabA, l15, quad, wiR, wiZ, wiN, aR, aZ, aNI);
                mm3_lds(slabB, l15, quad, whR, whZ, whN, aR, aZ, aNH);
                u16* dst = h1g + (long)(1 - c1p) * GS;
#pragma unroll
                for (int r = 0; r < 4; ++r) {
                    float rr = sigm(aR[r] + bir);
                    float zz = sigm(aZ[r] + biz);
                    float nn = tanh_f(aNI[r] + bin + rr * (aNH[r] + bhn));
                    float hv = (1.f - zz) * nn + zz * hf[r];
                    hf[r] = hv;
                    u16 hb = f2bf(hv);
                    store_u16_cc(dst + (long)(quad * 4 + r) * SS + sg, hb);
#pragma unroll
                    for (int i = 0; i < 15; ++i)
                        wreg[r][i] = (wreg[r][i] >> 16) | (wreg[r][i + 1] << 16);
                    wreg[r][15] = (wreg[r][15] >> 16) | ((u32)hb << 16);
                }
            }
        }
        group_bar(gf, rank, ++bar);
        if (p < 63) c0p ^= 1;
        if (p >= 1) c1p ^= 1;
    }

    // ================= decoder: d = 0..63, 2 phases each =================
    for (int d = 0; d < 64; ++d) {
        // ---- phase A: layer 0 (waves 0,1) ----
        if (d > 0) stage_issue(tsg, sv0);
        stage_issue(h0g + (long)c0p * GS, sv1);
        vm_drain();
        if (d > 0) stage_commit(slabA, sv0);
        stage_commit(slabB, sv1);
        __syncthreads();

        if (l0w) {
            if (d > 0) {   // gi(d) = gi(d-1) + M @ temp(d-1) + c0
                floatx4 tR = {0,0,0,0}, tZ = tR, tN = tR;
                mm3_lds(slabA, l15, quad, mR, mZ, mN, tR, tZ, tN);
#pragma unroll
                for (int r = 0; r < 4; ++r) {
                    gi[r] += tR[r] + c0r;
                    gi[4 + r] += tZ[r] + c0z;
                    gi[8 + r] += tN[r] + c0n;
                }
            }
            floatx4 hR = {0,0,0,0}, hZ = hR, hN4 = hR;
            mm3_lds(slabB, l15, quad, whR, whZ, whN, hR, hZ, hN4);
            u16* dst = h0g + (long)(1 - c0p) * GS;
#pragma unroll
            for (int r = 0; r < 4; ++r) {
                float rr = sigm(gi[r] + hR[r] + bir);
                float zz = sigm(gi[4 + r] + hZ[r] + biz);
                float nn = tanh_f(gi[8 + r] + bin + rr * (hN4[r] + bhn));
                float hv = (1.f - zz) * nn + zz * hf[r];
                hf[r] = hv;
                store_u16_cc(dst + (long)(quad * 4 + r) * SS + sg, f2bf(hv));
            }
        }
        group_bar(gf, rank, ++bar);
        c0p ^= 1;

        // ---- phase B: layer 1 + window/temp (waves 2,3) ----
        stage_issue(h0g + (long)c0p * GS, sv0);
        stage_issue(h1g + (long)c1p * GS, sv1);
        vm_drain();
        stage_commit(slabA, sv0);
        stage_commit(slabB, sv1);
        __syncthreads();

        if (!l0w) {
            floatx4 aR = {0,0,0,0}, aZ = aR, aNI = aR, aNH = aR;
            mm3_lds(slabA, l15, quad, wiR, wiZ, wiN, aR, aZ, aNI);
            mm3_lds(slabB, l15, quad, whR, whZ, whN, aR, aZ, aNH);
            u16* dst = h1g + (long)(1 - c1p) * GS;
            u16* tOut = temps + (long)d * (BB * SS);
#pragma unroll
            for (int r = 0; r < 4; ++r) {
                float rr = sigm(aR[r] + bir);
                float zz = sigm(aZ[r] + biz);
                float nn = tanh_f(aNI[r] + bin + rr * (aNH[r] + bhn));
                float hv = (1.f - zz) * nn + zz * hf[r];
                hf[r] = hv;
                u16 hb = f2bf(hv);
                store_u16_cc(dst + (long)(quad * 4 + r) * SS + sg, hb);
#pragma unroll
                for (int i = 0; i < 15; ++i)
                    wreg[r][i] = (wreg[r][i] >> 16) | (wreg[r][i + 1] << 16);
                wreg[r][15] = (wreg[r][15] >> 16) | ((u32)hb << 16);
                float tacc = btv;
#pragma unroll
                for (int i = 0; i < 16; ++i) {
                    u32 wv = wreg[r][i];
                    tacc += __uint_as_float(wv << 16) * wt[2 * i];
                    tacc += __uint_as_float(wv & 0xffff0000u) * wt[2 * i + 1];
                }
                u16 tb = f2bf(tacc);
                store_u16_cc(tsg + (long)(quad * 4 + r) * SS + sg, tb);
                tOut[(long)(b0g + quad * 4 + r) * SS + sg] = tb;  // cached
            }
        }
        group_bar(gf, rank, ++bar);
        c1p ^= 1;
    }
}

// ---------------------------------------------------------------------------
// frames epilogue (parallel): frames[b][e][c] = x_last[b][c]
//      + sum_{e'<=e} ( temp(e') @ Ws^T + bs )[c]
// ---------------------------------------------------------------------------
__global__ __launch_bounds__(256) void frames_kernel(
    const u16* __restrict__ temps, const float* __restrict__ x,
    const float* __restrict__ Ws, const float* __restrict__ bs,
    float* __restrict__ outp)
{
    const int b = blockIdx.x, tid = threadIdx.x;
    const int sc = tid >> 6, cs = tid & 63;
    __shared__ float part[4][128];
    float cum0 = x[((long)b * TT + (TT - 1)) * CC + cs];
    float cum1 = (cs < CC - 64) ? x[((long)b * TT + (TT - 1)) * CC + 64 + cs] : 0.f;
    const float bs0 = bs[cs];
    const float bs1 = (cs < CC - 64) ? bs[64 + cs] : 0.f;
    for (int e = 0; e < TT; ++e) {
        const u16* tr = temps + (long)e * (BB * SS) + (long)b * SS + sc * 128;
        float p0 = 0.f, p1 = 0.f;
        for (int i = 0; i < 128; ++i) {
            float tv = bf2f(tr[i]);
            p0 += tv * Ws[(long)cs * SS + sc * 128 + i];
            if (cs < CC - 64) p1 += tv * Ws[(long)(64 + cs) * SS + sc * 128 + i];
        }
        part[sc][cs] = p0;
        part[sc][64 + cs] = p1;
        __syncthreads();
        if (sc == 0) {
            cum0 += part[0][cs] + part[1][cs] + part[2][cs] + part[3][cs] + bs0;
            outp[(long)b * TT * CC + (long)e * CC + cs] = cum0;
            if (cs < CC - 64) {
                cum1 += part[0][64 + cs] + part[1][64 + cs] + part[2][64 + cs] +
                        part[3][64 + cs] + bs1;
                outp[(long)b * TT * CC + (long)e * CC + 64 + cs] = cum1;
            }
        }
        __syncthreads();
    }
}

// ---------------------------------------------------------------------------
extern "C" void kernel_launch(void* const* d_in, const int* in_sizes, int n_in,
                              void* d_out, int out_size, void* d_ws, size_t ws_size,
                              hipStream_t stream)
{
    const float* x    = (const float*)d_in[0];
    const float* Wih0 = (const float*)d_in[1];
    const float* Whh0 = (const float*)d_in[2];
    const float* bih0 = (const float*)d_in[3];
    const float* bhh0 = (const float*)d_in[4];
    const float* Wih1 = (const float*)d_in[5];
    const float* Whh1 = (const float*)d_in[6];
    const float* bih1 = (const float*)d_in[7];
    const float* bhh1 = (const float*)d_in[8];
    const float* Wt   = (const float*)d_in[9];
    const float* bt   = (const float*)d_in[10];
    const float* Ws   = (const float*)d_in[11];
    const float* bs   = (const float*)d_in[12];
    float* outp = (float*)d_out;

    char* p = (char*)d_ws;
    auto alloc = [&](size_t bytes) -> char* {
        char* r = p; p += (bytes + 255) & ~(size_t)255; return r;
    };
    u16* h0buf = (u16*)alloc((size_t)NGRP * 2 * GS * 2);
    u16* h1buf = (u16*)alloc((size_t)NGRP * 2 * GS * 2);
    u16* tstage = (u16*)alloc((size_t)NGRP * GS * 2);
    u16* xbf = (u16*)alloc((size_t)BB * TT * CPAD * 2);
    u16* wi0 = (u16*)alloc((size_t)NGATE * CPAD * 2);
    u16* wh0 = (u16*)alloc((size_t)NGATE * SS * 2);
    u16* wi1 = (u16*)alloc((size_t)NGATE * SS * 2);
    u16* wh1 = (u16*)alloc((size_t)NGATE * SS * 2);
    u16* Mbf = (u16*)alloc((size_t)NGATE * SS * 2);
    float* c0vec = (float*)alloc((size_t)NGATE * 4);
    float* gi0i  = (float*)alloc((size_t)BB * NGATE * 4);
    u16* temps = (u16*)alloc((size_t)TT * BB * SS * 2);
    int* gflags = (int*)alloc((size_t)NGRP * GBLK * 16 * 4);

    hipMemsetAsync(h0buf, 0, (size_t)NGRP * 2 * GS * 2, stream);
    hipMemsetAsync(h1buf, 0, (size_t)NGRP * 2 * GS * 2, stream);
    hipMemsetAsync(gflags, 0, (size_t)NGRP * GBLK * 16 * 4, stream);

    prep1_kernel<<<1024, 256, 0, stream>>>(x, Wih0, Whh0, Wih1, Whh1,
                                           xbf, wi0, wh0, wi1, wh1);
    prep2_kernel<<<1024, 256, 0, stream>>>(x, Wih0, Ws, bs, Mbf, c0vec, gi0i);

    persist_kernel<<<NGRP * GBLK, 256, 0, stream>>>(
        xbf, wi0, wh0, wi1, wh1, Mbf, bih0, bhh0, bih1, bhh1,
        c0vec, gi0i, Wt, bt, h0buf, h1buf, tstage, temps, gflags);

    frames_kernel<<<BB, 256, 0, stream>>>(temps, x, Ws, bs, outp);
}

// Round 6
// 2704.611 us; speedup vs baseline: 3.6553x; 1.6564x over previous
//
#include <hip/hip_runtime.h>
#include <stdint.h>

typedef unsigned short u16;
typedef uint32_t u32;
typedef __attribute__((ext_vector_type(8))) short short8;
typedef __attribute__((ext_vector_type(4))) float floatx4;

constexpr int BB = 128;     // batch
constexpr int TT = 64;      // time steps
constexpr int CC = 66;      // frame channels
constexpr int CPAD = 96;    // C padded to multiple of 32 (MFMA K-chunk)
constexpr int SS = 512;     // hidden
constexpr int NGATE = 1536; // 3*S
constexpr int NGRP = 8;     // independent batch groups (16 batches each)
constexpr int GBLK = 16;    // blocks per group (s-split by 32)
constexpr int GS = 16 * SS; // per-group state slab elements (16 x 512)
constexpr int NEG = -1000000;

__device__ __forceinline__ u16 f2bf(float f) {
    u32 u = __float_as_uint(f);
    u32 r = (u + 0x7fffu + ((u >> 16) & 1u)) >> 16;
    return (u16)r;
}
__device__ __forceinline__ float bf2f(u16 h) {
    return __uint_as_float(((u32)h) << 16);
}
__device__ __forceinline__ float sigm(float x) { return 1.f / (1.f + __expf(-x)); }
__device__ __forceinline__ float tanh_f(float x) { return 1.f - 2.f / (1.f + __expf(2.f * x)); }

// ---- coherence-bypass primitives (MALL-coherent, no cache maintenance) ----
__device__ __forceinline__ void store_u16_cc(u16* p, u16 v) {
    asm volatile("global_store_short %0, %1, off sc0 sc1"
                 :: "v"(p), "v"((u32)v) : "memory");
}
__device__ __forceinline__ void load_issue_cc(const u16* p, short8& d) {
    asm volatile("global_load_dwordx4 %0, %1, off sc0 sc1"
                 : "=v"(d) : "v"(p));
}
__device__ __forceinline__ void vm_drain() {
    asm volatile("s_waitcnt vmcnt(0)" ::: "memory");
}

// ---------------------------------------------------------------------------
// prep1: bf16 conversion of x (padded to 96), the 4 GRU weight matrices,
// and Ws -> bf16 [80][512] (c-padded) for the MFMA frames epilogue.
// ---------------------------------------------------------------------------
__global__ void prep1_kernel(const float* __restrict__ x,
                             const float* __restrict__ Wih0,
                             const float* __restrict__ Whh0,
                             const float* __restrict__ Wih1,
                             const float* __restrict__ Whh1,
                             const float* __restrict__ Ws,
                             u16* __restrict__ xbf, u16* __restrict__ wi0,
                             u16* __restrict__ wh0, u16* __restrict__ wi1,
                             u16* __restrict__ wh1, u16* __restrict__ wsb)
{
    const int N_xbf = BB * TT * CPAD;
    const int N_wi0 = NGATE * CPAD;
    const int N_whh = NGATE * SS;
    const int N_wsb = 80 * SS;
    const long total = (long)N_xbf + N_wi0 + 3L * N_whh + N_wsb;
    for (long i = (long)blockIdx.x * blockDim.x + threadIdx.x; i < total;
         i += (long)gridDim.x * blockDim.x) {
        long idx = i;
        if (idx < N_xbf) {
            int c = idx % CPAD; int bt = idx / CPAD;
            float v = (c < CC) ? x[(long)bt * CC + c] : 0.f;
            xbf[idx] = f2bf(v); continue;
        }
        idx -= N_xbf;
        if (idx < N_wi0) {
            int c = idx % CPAD; int n = idx / CPAD;
            float v = (c < CC) ? Wih0[(long)n * CC + c] : 0.f;
            wi0[idx] = f2bf(v); continue;
        }
        idx -= N_wi0;
        if (idx < N_whh) { wh0[idx] = f2bf(Whh0[idx]); continue; }
        idx -= N_whh;
        if (idx < N_whh) { wi1[idx] = f2bf(Wih1[idx]); continue; }
        idx -= N_whh;
        if (idx < N_whh) { wh1[idx] = f2bf(Whh1[idx]); continue; }
        idx -= N_whh;
        {
            int s = idx % SS; int c = idx / SS;
            wsb[idx] = (c < CC) ? f2bf(Ws[(long)c * SS + s]) : (u16)0;
        }
    }
}

// ---------------------------------------------------------------------------
// prep2: M = Wih0[:, :66] @ Ws (bf16); c0vec = Wih0 @ bs; gi0i = x_last@Wih0^T
// ---------------------------------------------------------------------------
__global__ void prep2_kernel(const float* __restrict__ x,
                             const float* __restrict__ Wih0,
                             const float* __restrict__ Ws,
                             const float* __restrict__ bs,
                             u16* __restrict__ Mbf, float* __restrict__ c0vec,
                             float* __restrict__ gi0i)
{
    const long NM = (long)NGATE * SS;
    const long NC = NGATE;
    const long NG = (long)BB * NGATE;
    const long total = NM + NC + NG;
    for (long i = (long)blockIdx.x * blockDim.x + threadIdx.x; i < total;
         i += (long)gridDim.x * blockDim.x) {
        long idx = i;
        if (idx < NM) {
            int s = idx % SS; int g = idx / SS;
            float acc = 0.f;
            for (int c = 0; c < CC; ++c)
                acc += Wih0[(long)g * CC + c] * Ws[(long)c * SS + s];
            Mbf[idx] = f2bf(acc); continue;
        }
        idx -= NM;
        if (idx < NC) {
            int g = idx;
            float acc = 0.f;
            for (int c = 0; c < CC; ++c) acc += Wih0[(long)g * CC + c] * bs[c];
            c0vec[g] = acc; continue;
        }
        idx -= NC;
        {
            int g = idx % NGATE; int b = idx / NGATE;
            float acc = 0.f;
            const float* xl = x + ((long)b * TT + (TT - 1)) * CC;
            for (int c = 0; c < CC; ++c) acc += xl[c] * Wih0[(long)g * CC + c];
            gi0i[idx] = acc;
        }
    }
}

// ---------------------------------------------------------------------------
// Per-WAVE flag wait: layer-0 flags (32 ints) polled by lanes 0..31,
// layer-1 flags by lanes 32..63, single combined spin.  Relaxed agent-scope
// loads (MALL-coherent, proven rounds 3-5).  No fences.
// ---------------------------------------------------------------------------
__device__ __forceinline__ void wait2(const int* __restrict__ f0, int t0,
                                      const int* __restrict__ f1, int t1) {
    const int lane = threadIdx.x & 63;
    const int* p = (lane < 32) ? (f0 + lane) : (f1 + (lane - 32));
    const int tgt = (lane < 32) ? t0 : t1;
    for (;;) {
        int v = __hip_atomic_load(p, __ATOMIC_RELAXED, __HIP_MEMORY_SCOPE_AGENT);
        if (__all(v >= tgt)) break;
        __builtin_amdgcn_s_sleep(1);
    }
    asm volatile("" ::: "memory");
}

__device__ __forceinline__ void set_flag(int* f, int v) {
    if ((threadIdx.x & 63) == 0)
        __hip_atomic_store(f, v, __ATOMIC_RELAXED, __HIP_MEMORY_SCOPE_AGENT);
}

// ---------------------------------------------------------------------------
// A-fragment direct load: 16 coherent dwordx4 per K=512 GEMM, straight into
// registers (no LDS round-trip).  a-layout: A[m=lane&15][k=quad*8+j].
// ---------------------------------------------------------------------------
__device__ __forceinline__ void load_afrags(const u16* __restrict__ st,
                                            int l15, int quad, short8* a) {
#pragma unroll
    for (int kc = 0; kc < 16; ++kc)
        load_issue_cc(st + (long)l15 * SS + kc * 32 + quad * 8, a[kc]);
}

#define MFMA_BF16(a, wp, acc) \
    acc = __builtin_amdgcn_mfma_f32_16x16x32_bf16(a, *(const short8*)(wp), acc, 0, 0, 0)

// Triple-gate MFMA over K=512 with register-resident A fragments.
__device__ __forceinline__ void mm3_reg(const short8* a,
                                        const u16* __restrict__ w0,
                                        const u16* __restrict__ w1,
                                        const u16* __restrict__ w2,
                                        floatx4& A0, floatx4& A1, floatx4& A2) {
#pragma unroll
    for (int kc = 0; kc < 16; ++kc) {
        const int k = kc << 5;
        MFMA_BF16(a[kc], w0 + k, A0);
        MFMA_BF16(a[kc], w1 + k, A1);
        MFMA_BF16(a[kc], w2 + k, A2);
    }
}

// Triple-gate MFMA, A direct from read-only cached global (x input, K=96).
template <int K>
__device__ __forceinline__ void mm3_g(const u16* __restrict__ aP,
                                      const u16* __restrict__ w0,
                                      const u16* __restrict__ w1,
                                      const u16* __restrict__ w2,
                                      floatx4& A0, floatx4& A1, floatx4& A2) {
#pragma unroll
    for (int k = 0; k < K; k += 32) {
        short8 a = *(const short8*)(aP + k);
        MFMA_BF16(a, w0 + k, A0);
        MFMA_BF16(a, w1 + k, A1);
        MFMA_BF16(a, w2 + k, A2);
    }
}

// ---------------------------------------------------------------------------
// Persistent kernel, wave-decoupled dataflow.  Group g = blockIdx>>4 owns
// batches [16g,16g+16); block rank = blockIdx&15 owns s-slice 32*rank..+32.
// Waves 0,1 = layer-0 (s-sub 0/1), waves 2,3 = layer-1.  Each wave runs its
// own step loop gated only by per-wave completion flags; no __syncthreads,
// no LDS.  Buffers: h0 depth 4 (L0 runs ahead up to 3), h1/tstage depth 2.
// ---------------------------------------------------------------------------
__global__ __launch_bounds__(256, 1) void persist_kernel(
    const u16* __restrict__ xbf,
    const u16* __restrict__ wi0, const u16* __restrict__ wh0,
    const u16* __restrict__ wi1, const u16* __restrict__ wh1,
    const u16* __restrict__ Mbf,
    const float* __restrict__ bih0, const float* __restrict__ bhh0,
    const float* __restrict__ bih1, const float* __restrict__ bhh1,
    const float* __restrict__ c0vec, const float* __restrict__ gi0i,
    const float* __restrict__ Wt, const float* __restrict__ bt,
    u16* __restrict__ h0buf,   // [NGRP][4][16][512]
    u16* __restrict__ h1buf,   // [NGRP][2][16][512]
    u16* __restrict__ tstage,  // [NGRP][2][16][512]
    u16* __restrict__ temps,   // [64][128][512] (cached; read by frames)
    int* __restrict__ gflags)  // [NGRP][64]: f0[32], f1[32]
{
    const int tid = threadIdx.x;
    const int wave = tid >> 6, lane = tid & 63;
    const int l15 = lane & 15, quad = lane >> 4;
    const int grp = blockIdx.x >> 4, rank = blockIdx.x & 15;
    const int b0g = grp * 16;
    const int wsub = wave & 1;
    const int sg = rank * 32 + wsub * 16 + l15;
    const bool l0w = wave < 2;

    u16* const h0g = h0buf + (long)grp * 4 * GS;
    u16* const h1g = h1buf + (long)grp * 2 * GS;
    u16* const tsg = tstage + (long)grp * 2 * GS;
    int* const f0 = gflags + grp * 64;
    int* const f1 = f0 + 32;
    const int myflag = rank * 2 + wsub;

    // ---- per-thread constants & register state ----
    float bir, biz, bin, bhn;
    float c0r = 0.f, c0z = 0.f, c0n = 0.f;
    float hf[4] = {0.f, 0.f, 0.f, 0.f};
    float gi[12];
    float wt[32]; float btv = 0.f;
    u32 wreg[4][16];
#pragma unroll
    for (int r = 0; r < 4; ++r)
#pragma unroll
        for (int i = 0; i < 16; ++i) wreg[r][i] = 0u;

    if (l0w) {
        bir = bih0[sg] + bhh0[sg];
        biz = bih0[512 + sg] + bhh0[512 + sg];
        bin = bih0[1024 + sg];
        bhn = bhh0[1024 + sg];
        c0r = c0vec[sg]; c0z = c0vec[512 + sg]; c0n = c0vec[1024 + sg];
#pragma unroll
        for (int g3 = 0; g3 < 3; ++g3)
#pragma unroll
            for (int r = 0; r < 4; ++r)
                gi[g3 * 4 + r] =
                    gi0i[(long)(b0g + quad * 4 + r) * NGATE + g3 * 512 + sg];
    } else {
        bir = bih1[sg] + bhh1[sg];
        biz = bih1[512 + sg] + bhh1[512 + sg];
        bin = bih1[1024 + sg];
        bhn = bhh1[1024 + sg];
#pragma unroll
        for (int j = 0; j < 32; ++j) wt[j] = Wt[j];
        btv = bt[0];
    }

    const u16 *wiR, *wiZ, *wiN, *whR, *whZ, *whN, *mR, *mZ, *mN;
    if (l0w) {
        wiR = wi0 + (long)sg * CPAD + quad * 8;
        wiZ = wi0 + (long)(512 + sg) * CPAD + quad * 8;
        wiN = wi0 + (long)(1024 + sg) * CPAD + quad * 8;
        whR = wh0 + (long)sg * SS + quad * 8;
        whZ = wh0 + (long)(512 + sg) * SS + quad * 8;
        whN = wh0 + (long)(1024 + sg) * SS + quad * 8;
        mR = Mbf + (long)sg * SS + quad * 8;
        mZ = Mbf + (long)(512 + sg) * SS + quad * 8;
        mN = Mbf + (long)(1024 + sg) * SS + quad * 8;
    } else {
        wiR = wi1 + (long)sg * SS + quad * 8;
        wiZ = wi1 + (long)(512 + sg) * SS + quad * 8;
        wiN = wi1 + (long)(1024 + sg) * SS + quad * 8;
        whR = wh1 + (long)sg * SS + quad * 8;
        whZ = wh1 + (long)(512 + sg) * SS + quad * 8;
        whN = wh1 + (long)(1024 + sg) * SS + quad * 8;
        mR = mZ = mN = nullptr;
    }

    short8 fa[16], fb[16];

    if (l0w) {
        // ================= layer-0 wave: 127 steps =================
        // encoder t = 0..62: consume h0(t), x[t]; produce h0(t+1)
        for (int t = 0; t < 63; ++t) {
            wait2(f0, t, f1, t - 3);   // data ready + depth-4 overwrite guard
            load_afrags(h0g + (long)(t & 3) * GS, l15, quad, fa);
            floatx4 aR = {0,0,0,0}, aZ = aR, aNI = aR, aNH = aR;
            const u16* aP = xbf + ((long)(b0g + l15) * TT + t) * CPAD + quad * 8;
            mm3_g<CPAD>(aP, wiR, wiZ, wiN, aR, aZ, aNI);
            vm_drain();
            mm3_reg(fa, whR, whZ, whN, aR, aZ, aNH);
            u16* dst = h0g + (long)((t + 1) & 3) * GS;
#pragma unroll
            for (int r = 0; r < 4; ++r) {
                float rr = sigm(aR[r] + bir);
                float zz = sigm(aZ[r] + biz);
                float nn = tanh_f(aNI[r] + bin + rr * (aNH[r] + bhn));
                float hv = (1.f - zz) * nn + zz * hf[r];
                hf[r] = hv;
                store_u16_cc(dst + (long)(quad * 4 + r) * SS + sg, f2bf(hv));
            }
            vm_drain();
            set_flag(f0 + myflag, t + 1);
        }
        // decoder d = 0..63: step index t = 63+d; produce h0 state 64+d
        for (int d = 0; d < 64; ++d) {
            const int t = 63 + d;
            wait2(f0, t, f1, (d > 0) ? t : 60);
            if (d > 0) {
                load_afrags(tsg + (long)((d - 1) & 1) * GS, l15, quad, fb);
            }
            load_afrags(h0g + (long)(t & 3) * GS, l15, quad, fa);
            vm_drain();
            if (d > 0) {   // gi(d) = gi(d-1) + M @ temp(d-1) + c0
                floatx4 tR = {0,0,0,0}, tZ = tR, tN = tR;
                mm3_reg(fb, mR, mZ, mN, tR, tZ, tN);
#pragma unroll
                for (int r = 0; r < 4; ++r) {
                    gi[r] += tR[r] + c0r;
                    gi[4 + r] += tZ[r] + c0z;
                    gi[8 + r] += tN[r] + c0n;
                }
            }
            floatx4 hR = {0,0,0,0}, hZ = hR, hN4 = hR;
            mm3_reg(fa, whR, whZ, whN, hR, hZ, hN4);
            u16* dst = h0g + (long)((t + 1) & 3) * GS;
#pragma unroll
            for (int r = 0; r < 4; ++r) {
                float rr = sigm(gi[r] + hR[r] + bir);
                float zz = sigm(gi[4 + r] + hZ[r] + biz);
                float nn = tanh_f(gi[8 + r] + bin + rr * (hN4[r] + bhn));
                float hv = (1.f - zz) * nn + zz * hf[r];
                hf[r] = hv;
                store_u16_cc(dst + (long)(quad * 4 + r) * SS + sg, f2bf(hv));
            }
            vm_drain();
            set_flag(f0 + myflag, t + 1);
        }
    } else {
        // ================= layer-1 wave: 127 steps =================
        // encoder u = 0..62: consume h0(u+1), h1(u); produce h1(u+1) + window
        for (int u = 0; u < 63; ++u) {
            wait2(f0, u + 1, f1, u);
            load_afrags(h0g + (long)((u + 1) & 3) * GS, l15, quad, fa);
            load_afrags(h1g + (long)(u & 1) * GS, l15, quad, fb);
            vm_drain();
            floatx4 aR = {0,0,0,0}, aZ = aR, aNI = aR, aNH = aR;
            mm3_reg(fa, wiR, wiZ, wiN, aR, aZ, aNI);
            mm3_reg(fb, whR, whZ, whN, aR, aZ, aNH);
            u16* dst = h1g + (long)((u + 1) & 1) * GS;
#pragma unroll
            for (int r = 0; r < 4; ++r) {
                float rr = sigm(aR[r] + bir);
                float zz = sigm(aZ[r] + biz);
                float nn = tanh_f(aNI[r] + bin + rr * (aNH[r] + bhn));
                float hv = (1.f - zz) * nn + zz * hf[r];
                hf[r] = hv;
                u16 hb = f2bf(hv);
                store_u16_cc(dst + (long)(quad * 4 + r) * SS + sg, hb);
#pragma unroll
                for (int i = 0; i < 15; ++i)
                    wreg[r][i] = (wreg[r][i] >> 16) | (wreg[r][i + 1] << 16);
                wreg[r][15] = (wreg[r][15] >> 16) | ((u32)hb << 16);
            }
            vm_drain();
            set_flag(f1 + myflag, u + 1);
        }
        // decoder d = 0..63: step u = 63+d; produce h1(64+d), temp(d)
        for (int d = 0; d < 64; ++d) {
            const int u = 63 + d;
            wait2(f0, u + 1, f1, u);
            load_afrags(h0g + (long)((u + 1) & 3) * GS, l15, quad, fa);
            load_afrags(h1g + (long)(u & 1) * GS, l15, quad, fb);
            vm_drain();
            floatx4 aR = {0,0,0,0}, aZ = aR, aNI = aR, aNH = aR;
            mm3_reg(fa, wiR, wiZ, wiN, aR, aZ, aNI);
            mm3_reg(fb, whR, whZ, whN, aR, aZ, aNH);
            u16* dst = h1g + (long)((u + 1) & 1) * GS;
            u16* tdst = tsg + (long)(d & 1) * GS;
            u16* tOut = temps + (long)d * (BB * SS);
#pragma unroll
            for (int r = 0; r < 4; ++r) {
                float rr = sigm(aR[r] + bir);
                float zz = sigm(aZ[r] + biz);
                float nn = tanh_f(aNI[r] + bin + rr * (aNH[r] + bhn));
                float hv = (1.f - zz) * nn + zz * hf[r];
                hf[r] = hv;
                u16 hb = f2bf(hv);
                store_u16_cc(dst + (long)(quad * 4 + r) * SS + sg, hb);
#pragma unroll
                for (int i = 0; i < 15; ++i)
                    wreg[r][i] = (wreg[r][i] >> 16) | (wreg[r][i + 1] << 16);
                wreg[r][15] = (wreg[r][15] >> 16) | ((u32)hb << 16);
                float tacc = btv;
#pragma unroll
                for (int i = 0; i < 16; ++i) {
                    u32 wv = wreg[r][i];
                    tacc += __uint_as_float(wv << 16) * wt[2 * i];
                    tacc += __uint_as_float(wv & 0xffff0000u) * wt[2 * i + 1];
                }
                u16 tb = f2bf(tacc);
                store_u16_cc(tdst + (long)(quad * 4 + r) * SS + sg, tb);
                tOut[(long)(b0g + quad * 4 + r) * SS + sg] = tb;  // cached
            }
            vm_drain();
            set_flag(f1 + myflag, u + 1);
        }
    }
}

// ---------------------------------------------------------------------------
// frames epilogue (parallel, MFMA): per batch b,
//   P[e][c] = temp(e)[b] . Ws[c];  frames[b][e][c] = x_last + cumsum(P + bs)
// Wave w computes e-tile w (16 e-rows) x 5 c-tiles via 16x16x32 MFMA.
// ---------------------------------------------------------------------------
__global__ __launch_bounds__(256) void frames_kernel(
    const u16* __restrict__ temps, const float* __restrict__ x,
    const u16* __restrict__ wsb, const float* __restrict__ bs,
    float* __restrict__ outp)
{
    const int b = blockIdx.x, tid = threadIdx.x;
    const int wave = tid >> 6, lane = tid & 63;
    const int l15 = lane & 15, quad = lane >> 4;
    __shared__ float P[64][81];

    const int e0 = wave * 16;
    floatx4 acc[5];
#pragma unroll
    for (int ct = 0; ct < 5; ++ct) acc[ct] = (floatx4){0.f, 0.f, 0.f, 0.f};
    const u16* aBase =
        temps + (long)(e0 + l15) * (BB * SS) + (long)b * SS + quad * 8;
#pragma unroll
    for (int kc = 0; kc < 16; ++kc) {
        short8 a = *(const short8*)(aBase + kc * 32);
#pragma unroll
        for (int ct = 0; ct < 5; ++ct) {
            const u16* wp = wsb + (long)(ct * 16 + l15) * SS + quad * 8 + kc * 32;
            MFMA_BF16(a, wp, acc[ct]);
        }
    }
#pragma unroll
    for (int ct = 0; ct < 5; ++ct)
#pragma unroll
        for (int r = 0; r < 4; ++r)
            P[e0 + quad * 4 + r][ct * 16 + l15] = acc[ct][r];
    __syncthreads();

    const int c = tid;
    if (c < CC) {
        float cum = x[((long)b * TT + (TT - 1)) * CC + c];
        const float bsv = bs[c];
        for (int e = 0; e < TT; ++e) {
            cum += P[e][c] + bsv;
            outp[(long)b * TT * CC + (long)e * CC + c] = cum;
        }
    }
}

// ---------------------------------------------------------------------------
extern "C" void kernel_launch(void* const* d_in, const int* in_sizes, int n_in,
                              void* d_out, int out_size, void* d_ws, size_t ws_size,
                              hipStream_t stream)
{
    const float* x    = (const float*)d_in[0];
    const float* Wih0 = (const float*)d_in[1];
    const float* Whh0 = (const float*)d_in[2];
    const float* bih0 = (const float*)d_in[3];
    const float* bhh0 = (const float*)d_in[4];
    const float* Wih1 = (const float*)d_in[5];
    const float* Whh1 = (const float*)d_in[6];
    const float* bih1 = (const float*)d_in[7];
    const float* bhh1 = (const float*)d_in[8];
    const float* Wt   = (const float*)d_in[9];
    const float* bt   = (const float*)d_in[10];
    const float* Ws   = (const float*)d_in[11];
    const float* bs   = (const float*)d_in[12];
    float* outp = (float*)d_out;

    char* p = (char*)d_ws;
    auto alloc = [&](size_t bytes) -> char* {
        char* r = p; p += (bytes + 255) & ~(size_t)255; return r;
    };
    u16* h0buf = (u16*)alloc((size_t)NGRP * 4 * GS * 2);
    u16* h1buf = (u16*)alloc((size_t)NGRP * 2 * GS * 2);
    u16* tstage = (u16*)alloc((size_t)NGRP * 2 * GS * 2);
    u16* xbf = (u16*)alloc((size_t)BB * TT * CPAD * 2);
    u16* wi0 = (u16*)alloc((size_t)NGATE * CPAD * 2);
    u16* wh0 = (u16*)alloc((size_t)NGATE * SS * 2);
    u16* wi1 = (u16*)alloc((size_t)NGATE * SS * 2);
    u16* wh1 = (u16*)alloc((size_t)NGATE * SS * 2);
    u16* Mbf = (u16*)alloc((size_t)NGATE * SS * 2);
    u16* wsb = (u16*)alloc((size_t)80 * SS * 2);
    float* c0vec = (float*)alloc((size_t)NGATE * 4);
    float* gi0i  = (float*)alloc((size_t)BB * NGATE * 4);
    u16* temps = (u16*)alloc((size_t)TT * BB * SS * 2);
    int* gflags = (int*)alloc((size_t)NGRP * 64 * 4);

    hipMemsetAsync(h0buf, 0, (size_t)NGRP * 4 * GS * 2, stream);
    hipMemsetAsync(h1buf, 0, (size_t)NGRP * 2 * GS * 2, stream);
    hipMemsetAsync(gflags, 0, (size_t)NGRP * 64 * 4, stream);

    prep1_kernel<<<1024, 256, 0, stream>>>(x, Wih0, Whh0, Wih1, Whh1, Ws,
                                           xbf, wi0, wh0, wi1, wh1, wsb);
    prep2_kernel<<<1024, 256, 0, stream>>>(x, Wih0, Ws, bs, Mbf, c0vec, gi0i);

    persist_kernel<<<NGRP * GBLK, 256, 0, stream>>>(
        xbf, wi0, wh0, wi1, wh1, Mbf, bih0, bhh0, bih1, bhh1,
        c0vec, gi0i, Wt, bt, h0buf, h1buf, tstage, temps, gflags);

    frames_kernel<<<BB, 256, 0, stream>>>(temps, x, wsb, bs, outp);
}